// Round 4
// baseline (798.680 us; speedup 1.0000x reference)
//
#include <hip/hip_runtime.h>

// MemoAI fused block for MI355X (gfx950).
//  - fp16x2 split-precision MFMA (hi + 2^11-scaled lo) upstream of MoE routing
//  - plain fp16 MFMA for the expert FFN (post-routing)
//  - sum(softmax(top2)) == 1 -> moe weight multiplier is exactly 1
//  - only the chosen expert is computed (tokens bucketed by expert)
//  - R1: 64x128 LDS-staged GEMM core (global_load_lds width=16)
//  - R2: flash attention (online softmax, register scores), qscale fused
//  - R3: split-K on gate/outp/moe1/moe2 (fp32 partial buffers, reductions
//    folded into the elementwise consumers) -> 2-5 active blocks/CU instead
//    of 1 (fixes MfmaUtil 2.7% / Occupancy 6.7% latency-bound K-loop).

typedef _Float16 f16;
typedef _Float16 f16x8 __attribute__((ext_vector_type(8)));
typedef _Float16 f16x4 __attribute__((ext_vector_type(4)));
typedef float f32x4 __attribute__((ext_vector_type(4)));

constexpr int CS  = 1024;  // seq len
constexpr int CD  = 1024;  // model dim
constexpr int CH  = 16;    // heads
constexpr int CHD = 64;    // head dim
constexpr int CF  = 2048;  // ffn dim
constexpr int CE  = 8;     // experts
constexpr int CN  = 2048;  // tokens = B*S
constexpr int CBH = 32;    // B*H
constexpr int KS  = 512;   // split-K slice width

constexpr float LO_SCALE = 2048.f;       // 2^11: keeps lo-parts normal in fp16
constexpr float LO_INV   = 1.f / 2048.f;

#define MFMA16(a, b, c) __builtin_amdgcn_mfma_f32_16x16x32_f16((a), (b), (c), 0, 0, 0)

#define TO_GBL(p) ((const __attribute__((address_space(1))) void*)(p))
#define TO_LDS(p) ((__attribute__((address_space(3))) void*)(p))
#define GLD16(g, l) __builtin_amdgcn_global_load_lds(TO_GBL(g), TO_LDS(l), 16, 0, 0)

__device__ __forceinline__ void fsplit(float v, f16 &hi, f16 &lo) {
  hi = (f16)v;
  lo = (f16)((v - (float)hi) * LO_SCALE);
}

// ---------------------------------------------------------------- conversions

__global__ void k_split_cvt(const float* __restrict__ in, f16* __restrict__ oh,
                            f16* __restrict__ ol, int n) {
  int i = (blockIdx.x * blockDim.x + threadIdx.x) * 4;
  if (i >= n) return;
  float4 v = *(const float4*)(in + i);
  float a[4] = {v.x, v.y, v.z, v.w};
#pragma unroll
  for (int j = 0; j < 4; ++j) {
    f16 hi = (f16)a[j];
    oh[i + j] = hi;
    ol[i + j] = (f16)((a[j] - (float)hi) * LO_SCALE);
  }
}

// in: [Z][R][C] f32 -> outH(/outL scaled) : [Z][C][R] f16
__global__ void k_transpose_split(const float* __restrict__ in, f16* __restrict__ oh,
                                  f16* __restrict__ ol, int R, int C) {
  __shared__ float t[32][33];
  const int z = blockIdx.z;
  const float* src = in + (size_t)z * R * C;
  f16* dh = oh + (size_t)z * R * C;
  f16* dl = ol ? ol + (size_t)z * R * C : nullptr;
  const int c0 = blockIdx.x * 32, r0 = blockIdx.y * 32;
  const int tx = threadIdx.x, ty = threadIdx.y;
#pragma unroll
  for (int i = 0; i < 32; i += 8)
    t[ty + i][tx] = src[(size_t)(r0 + ty + i) * C + c0 + tx];
  __syncthreads();
#pragma unroll
  for (int i = 0; i < 32; i += 8) {
    float v = t[tx][ty + i];
    f16 hi = (f16)v;
    size_t idx = (size_t)(c0 + ty + i) * R + r0 + tx;
    dh[idx] = hi;
    if (dl) dl[idx] = (f16)((v - (float)hi) * LO_SCALE);
  }
}

// ------------------------------------------------------------- tiled GEMM core
// Block tile 64(M) x 128(N), BK=32, 4 waves (2x2), wave tile 32x64.

template <bool SPLIT>
__device__ __forceinline__ void gemm_tile(
    const f16* aH, const f16* aL, const f16* bH, const f16* bL,
    size_t bRowStride /* 64*ldb */, int K, f16* lds,
    f32x4 (&accm)[2][4], f32x4 (&accc)[2][4]) {
  f16* lAh = lds;                          // 64*32  = 2048 halves
  f16* lAl = lds + 2048;                   // (split only)
  f16* lBh = lds + (SPLIT ? 4096 : 2048);  // 128*32 = 4096 halves
  f16* lBl = lds + 8192;                   // (split only)
  const int t = threadIdx.x;
  const int lane = t & 63, wave = t >> 6;
  const int wm = wave >> 1, wn = wave & 1;
  const int m16 = lane & 15, quad = lane >> 4;
  int aoff[2], boff[4];
#pragma unroll
  for (int sm = 0; sm < 2; ++sm) {
    const int r = wm * 32 + sm * 16 + m16;
    aoff[sm] = r * 32 + ((quad ^ ((r >> 1) & 3)) * 8);
  }
#pragma unroll
  for (int sn = 0; sn < 4; ++sn) {
    const int r = wn * 64 + sn * 16 + m16;
    boff[sn] = r * 32 + ((quad ^ ((r >> 1) & 3)) * 8);
  }
  for (int k = 0; k < K; k += 32) {
    GLD16(aH, lAh + t * 8);
    GLD16(bH, lBh + t * 8);
    GLD16(bH + bRowStride, lBh + 2048 + t * 8);
    if constexpr (SPLIT) {
      GLD16(aL, lAl + t * 8);
      GLD16(bL, lBl + t * 8);
      GLD16(bL + bRowStride, lBl + 2048 + t * 8);
      aL += 32; bL += 32;
    }
    aH += 32; bH += 32;
    __syncthreads();  // drains vmcnt(0) -> staged data visible
    f16x8 af[2], alf[2], bf[4], blf[4];
#pragma unroll
    for (int sm = 0; sm < 2; ++sm) {
      af[sm] = *(const f16x8*)(lAh + aoff[sm]);
      if constexpr (SPLIT) alf[sm] = *(const f16x8*)(lAl + aoff[sm]);
    }
#pragma unroll
    for (int sn = 0; sn < 4; ++sn) {
      bf[sn] = *(const f16x8*)(lBh + boff[sn]);
      if constexpr (SPLIT) blf[sn] = *(const f16x8*)(lBl + boff[sn]);
    }
#pragma unroll
    for (int sm = 0; sm < 2; ++sm)
#pragma unroll
      for (int sn = 0; sn < 4; ++sn) {
        accm[sm][sn] = MFMA16(af[sm], bf[sn], accm[sm][sn]);
        if constexpr (SPLIT) {
          accc[sm][sn] = MFMA16(af[sm], blf[sn], accc[sm][sn]);
          accc[sm][sn] = MFMA16(alf[sm], bf[sn], accc[sm][sn]);
        }
      }
    __syncthreads();  // all waves done reading before next overwrite
  }
}

// ---------------------------------------------------------------- QKV

__global__ __launch_bounds__(256) void g_qkv(
    const f16* __restrict__ srcH, const f16* __restrict__ srcL,
    const f16* __restrict__ qwH, const f16* __restrict__ qwL,
    const f16* __restrict__ kwH, const f16* __restrict__ kwL,
    const f16* __restrict__ vwH, const f16* __restrict__ vwL,
    f16* __restrict__ qHo, f16* __restrict__ qLo,
    f16* __restrict__ kHo, f16* __restrict__ kLo,
    f16* __restrict__ vTH, f16* __restrict__ vTL) {
  __shared__ f16 lds[12288];
  const int z = blockIdx.z;
  const int m0 = blockIdx.x * 64, n0 = blockIdx.y * 128;
  const int t = threadIdx.x;
  const int rowS = t >> 2;
  const int ksw = ((t & 3) ^ ((rowS >> 1) & 3)) * 8;
  const f16* BH = (z == 0) ? qwH : (z == 1) ? kwH : vwH;
  const f16* BL = (z == 0) ? qwL : (z == 1) ? kwL : vwL;
  const f32x4 VZ = {0.f, 0.f, 0.f, 0.f};
  f32x4 accm[2][4], accc[2][4];
#pragma unroll
  for (int i = 0; i < 2; ++i)
#pragma unroll
    for (int j = 0; j < 4; ++j) { accm[i][j] = VZ; accc[i][j] = VZ; }
  gemm_tile<true>(srcH + (size_t)(m0 + rowS) * CD + ksw,
                  srcL + (size_t)(m0 + rowS) * CD + ksw,
                  BH + (size_t)(n0 + rowS) * CD + ksw,
                  BL + (size_t)(n0 + rowS) * CD + ksw,
                  (size_t)64 * CD, CD, lds, accm, accc);
  const int lane = t & 63, wave = t >> 6;
  const int wm = wave >> 1, wn = wave & 1;
  const int m16 = lane & 15, quad = lane >> 4;
#pragma unroll
  for (int sm = 0; sm < 2; ++sm)
#pragma unroll
    for (int sn = 0; sn < 4; ++sn)
#pragma unroll
      for (int r = 0; r < 4; ++r) {
        const int row = m0 + wm * 32 + sm * 16 + quad * 4 + r;  // token
        const int col = n0 + wn * 64 + sn * 16 + m16;           // d
        const float v = accm[sm][sn][r] + accc[sm][sn][r] * LO_INV;
        f16 hi, lo; fsplit(v, hi, lo);
        const int bb = row >> 10, ss = row & 1023;
        const int hh = col >> 6, hd = col & 63;
        if (z == 2) {  // v stored transposed: [b,h,hd,s]
          const size_t idx = ((size_t)((bb * CH + hh) * CHD + hd)) * CS + ss;
          vTH[idx] = hi; vTL[idx] = lo;
        } else {
          const size_t idx = ((size_t)((bb * CH + hh) * CS + ss)) * CHD + hd;
          if (z == 0) { qHo[idx] = hi; qLo[idx] = lo; }
          else        { kHo[idx] = hi; kLo[idx] = lo; }
        }
      }
}

// ------------------------------------------------------- flash attention

__device__ __forceinline__ int pswz(int q, int k) {
  return q * 64 + ((((k >> 2) ^ q) & 15) << 2) + (k & 3);
}

__global__ __launch_bounds__(256) void k_fattn(
    const f16* __restrict__ qH_, const f16* __restrict__ qL_,
    const f16* __restrict__ kH_, const f16* __restrict__ kL_,
    const f16* __restrict__ vTH_, const f16* __restrict__ vTL_,
    const float* __restrict__ scale_w,
    f16* __restrict__ aoH, f16* __restrict__ aoL) {
  __shared__ float psc[4 * 1024];  // 4 waves x (16x64) P tile, swizzled
  const int bh = blockIdx.y;
  const int b = bh >> 4, h = bh & 15;
  const int lane = threadIdx.x & 63, wave = threadIdx.x >> 6;
  const int m16 = lane & 15, quad = lane >> 4;
  const int q0 = blockIdx.x * 64 + wave * 16;  // this wave's q rows
  float* P = psc + wave * 1024;
  const f32x4 VZ = {0.f, 0.f, 0.f, 0.f};

  const f16* qrh = qH_ + ((size_t)bh * CS + q0 + m16) * CHD + quad * 8;
  const f16* qrl = qL_ + ((size_t)bh * CS + q0 + m16) * CHD + quad * 8;
  f16x8 a0h = *(const f16x8*)(qrh);
  f16x8 a1h = *(const f16x8*)(qrh + 32);
  f16x8 a0l = *(const f16x8*)(qrl);
  f16x8 a1l = *(const f16x8*)(qrl + 32);

  // fused dynamic scale: row factor = 2*sigmoid(q . scale_w[h]) / sqrt(64)
  float dot = 0.f;
  {
    const float* sw = scale_w + h * CHD + quad * 8;
    float4 s0 = *(const float4*)(sw);
    float4 s1 = *(const float4*)(sw + 4);
    float4 s2 = *(const float4*)(sw + 32);
    float4 s3 = *(const float4*)(sw + 36);
    float sv[16] = {s0.x, s0.y, s0.z, s0.w, s1.x, s1.y, s1.z, s1.w,
                    s2.x, s2.y, s2.z, s2.w, s3.x, s3.y, s3.z, s3.w};
#pragma unroll
    for (int j = 0; j < 8; ++j) {
      dot += ((float)a0h[j] + (float)a0l[j] * LO_INV) * sv[j];
      dot += ((float)a1h[j] + (float)a1l[j] * LO_INV) * sv[8 + j];
    }
    dot += __shfl_xor(dot, 16);
    dot += __shfl_xor(dot, 32);
  }
  const float qsv = 2.f / (1.f + __expf(-dot));  // for row q0+m16
  float qsr[4];
#pragma unroll
  for (int r = 0; r < 4; ++r) qsr[r] = __shfl(qsv, quad * 4 + r) * 0.125f;

  f32x4 accm[4], accc[4];  // out accumulator: 4 hd-tiles, C-layout
#pragma unroll
  for (int t = 0; t < 4; ++t) { accm[t] = VZ; accc[t] = VZ; }
  float mrun[4], lrun[4];
#pragma unroll
  for (int r = 0; r < 4; ++r) { mrun[r] = -1e30f; lrun[r] = 0.f; }

  for (int kc = 0; kc < CS; kc += 64) {
    f32x4 st[4];
#pragma unroll
    for (int t = 0; t < 4; ++t) {
      const f16* krh = kH_ + ((size_t)bh * CS + kc + t * 16 + m16) * CHD + quad * 8;
      const f16* krl = kL_ + ((size_t)bh * CS + kc + t * 16 + m16) * CHD + quad * 8;
      f16x8 b0h = *(const f16x8*)(krh);
      f16x8 b1h = *(const f16x8*)(krh + 32);
      f16x8 b0l = *(const f16x8*)(krl);
      f16x8 b1l = *(const f16x8*)(krl + 32);
      f32x4 am = VZ, ac = VZ;
      am = MFMA16(a0h, b0h, am); am = MFMA16(a1h, b1h, am);
      ac = MFMA16(a0h, b0l, ac); ac = MFMA16(a0l, b0h, ac);
      ac = MFMA16(a1h, b1l, ac); ac = MFMA16(a1l, b1h, ac);
#pragma unroll
      for (int r = 0; r < 4; ++r)
        st[t][r] = (am[r] + ac[r] * LO_INV) * qsr[r];
    }
    float alpha[4];
#pragma unroll
    for (int r = 0; r < 4; ++r) {
      float mx = fmaxf(fmaxf(st[0][r], st[1][r]), fmaxf(st[2][r], st[3][r]));
#pragma unroll
      for (int msk = 8; msk >= 1; msk >>= 1) mx = fmaxf(mx, __shfl_xor(mx, msk));
      const float mnew = fmaxf(mrun[r], mx);
      alpha[r] = __expf(mrun[r] - mnew);
      mrun[r] = mnew;
    }
    float rs[4] = {0.f, 0.f, 0.f, 0.f};
#pragma unroll
    for (int t = 0; t < 4; ++t)
#pragma unroll
      for (int r = 0; r < 4; ++r) {
        const float e = __expf(st[t][r] - mrun[r]);
        rs[r] += e;
        P[pswz(quad * 4 + r, t * 16 + m16)] = e;
      }
#pragma unroll
    for (int r = 0; r < 4; ++r) {
#pragma unroll
      for (int msk = 8; msk >= 1; msk >>= 1) rs[r] += __shfl_xor(rs[r], msk);
      lrun[r] = lrun[r] * alpha[r] + rs[r];
#pragma unroll
      for (int t = 0; t < 4; ++t) { accm[t][r] *= alpha[r]; accc[t][r] *= alpha[r]; }
    }
    f16x8 pah[2], pal[2];
#pragma unroll
    for (int c = 0; c < 2; ++c) {
      const int k0 = c * 32 + quad * 8;
      float4 p0 = *(const float4*)(P + pswz(m16, k0));
      float4 p1 = *(const float4*)(P + pswz(m16, k0 + 4));
      float pv[8] = {p0.x, p0.y, p0.z, p0.w, p1.x, p1.y, p1.z, p1.w};
#pragma unroll
      for (int j = 0; j < 8; ++j) {
        f16 hi = (f16)pv[j];
        pah[c][j] = hi;
        pal[c][j] = (f16)((pv[j] - (float)hi) * LO_SCALE);
      }
    }
#pragma unroll
    for (int t = 0; t < 4; ++t) {
      const f16* vrh = vTH_ + ((size_t)bh * CHD + t * 16 + m16) * CS + kc + quad * 8;
      const f16* vrl = vTL_ + ((size_t)bh * CHD + t * 16 + m16) * CS + kc + quad * 8;
#pragma unroll
      for (int c = 0; c < 2; ++c) {
        f16x8 vbh = *(const f16x8*)(vrh + c * 32);
        f16x8 vbl = *(const f16x8*)(vrl + c * 32);
        accm[t] = MFMA16(pah[c], vbh, accm[t]);
        accc[t] = MFMA16(pah[c], vbl, accc[t]);
        accc[t] = MFMA16(pal[c], vbh, accc[t]);
      }
    }
  }
#pragma unroll
  for (int t = 0; t < 4; ++t)
#pragma unroll
    for (int r = 0; r < 4; ++r) {
      const int row = q0 + quad * 4 + r;
      const float v = (accm[t][r] + accc[t][r] * LO_INV) / lrun[r];
      f16 hi, lo; fsplit(v, hi, lo);
      const size_t idx = ((size_t)(b * CS + row)) * CD + h * CHD + t * 16 + m16;
      aoH[idx] = hi; aoL[idx] = lo;
    }
}

// ------------------------------------------- gate / out (split-K partials)

__global__ __launch_bounds__(256) void g_gate(
    const f16* __restrict__ aoH, const f16* __restrict__ aoL,
    const f16* __restrict__ gwH, const f16* __restrict__ gwL,
    float* __restrict__ gpre /* [2][CN*CD] */) {
  __shared__ f16 lds[12288];
  const int m0 = blockIdx.x * 64, n0 = blockIdx.y * 128, s = blockIdx.z;
  const int t = threadIdx.x;
  const int rowS = t >> 2;
  const int ksw = ((t & 3) ^ ((rowS >> 1) & 3)) * 8;
  const int k0 = s * KS;
  const f32x4 VZ = {0.f, 0.f, 0.f, 0.f};
  f32x4 accm[2][4], accc[2][4];
#pragma unroll
  for (int i = 0; i < 2; ++i)
#pragma unroll
    for (int j = 0; j < 4; ++j) { accm[i][j] = VZ; accc[i][j] = VZ; }
  gemm_tile<true>(aoH + (size_t)(m0 + rowS) * CD + k0 + ksw,
                  aoL + (size_t)(m0 + rowS) * CD + k0 + ksw,
                  gwH + (size_t)(n0 + rowS) * CD + k0 + ksw,
                  gwL + (size_t)(n0 + rowS) * CD + k0 + ksw,
                  (size_t)64 * CD, KS, lds, accm, accc);
  float* gp = gpre + (size_t)s * CN * CD;
  const int lane = t & 63, wave = t >> 6;
  const int wm = wave >> 1, wn = wave & 1;
  const int m16 = lane & 15, quad = lane >> 4;
#pragma unroll
  for (int sm = 0; sm < 2; ++sm)
#pragma unroll
    for (int sn = 0; sn < 4; ++sn)
#pragma unroll
      for (int r = 0; r < 4; ++r) {
        const int row = m0 + wm * 32 + sm * 16 + quad * 4 + r;
        const int col = n0 + wn * 64 + sn * 16 + m16;
        gp[(size_t)row * CD + col] = accm[sm][sn][r] + accc[sm][sn][r] * LO_INV;
      }
}

// gd = fsplit(ao * sigmoid(gpre0+gpre1+gate_b))
__global__ __launch_bounds__(256) void k_gatemul(
    const float* __restrict__ gpre, const f16* __restrict__ aoH,
    const f16* __restrict__ aoL, const float* __restrict__ gate_b,
    f16* __restrict__ gdH, f16* __restrict__ gdL) {
  const int i = (blockIdx.x * 256 + threadIdx.x) * 4;
  float4 p0 = *(const float4*)(gpre + i);
  float4 p1 = *(const float4*)(gpre + (size_t)CN * CD + i);
  float4 gb = *(const float4*)(gate_b + (i & (CD - 1)));
  f16x4 ah = *(const f16x4*)(aoH + i);
  f16x4 al = *(const f16x4*)(aoL + i);
  float pre[4] = {p0.x + p1.x + gb.x, p0.y + p1.y + gb.y,
                  p0.z + p1.z + gb.z, p0.w + p1.w + gb.w};
  f16x4 oh, ol;
#pragma unroll
  for (int j = 0; j < 4; ++j) {
    const float g = 1.f / (1.f + __expf(-pre[j]));
    const float ov = ((float)ah[j] + (float)al[j] * LO_INV) * g;
    f16 hi, lo; fsplit(ov, hi, lo);
    oh[j] = hi; ol[j] = lo;
  }
  *(f16x4*)(gdH + i) = oh;
  *(f16x4*)(gdL + i) = ol;
}

__global__ __launch_bounds__(256) void g_outp(
    const f16* __restrict__ gdH, const f16* __restrict__ gdL,
    const f16* __restrict__ owH, const f16* __restrict__ owL,
    float* __restrict__ y1p /* [2][CN*CD] */) {
  __shared__ f16 lds[12288];
  const int m0 = blockIdx.x * 64, n0 = blockIdx.y * 128, s = blockIdx.z;
  const int t = threadIdx.x;
  const int rowS = t >> 2;
  const int ksw = ((t & 3) ^ ((rowS >> 1) & 3)) * 8;
  const int k0 = s * KS;
  const f32x4 VZ = {0.f, 0.f, 0.f, 0.f};
  f32x4 accm[2][4], accc[2][4];
#pragma unroll
  for (int i = 0; i < 2; ++i)
#pragma unroll
    for (int j = 0; j < 4; ++j) { accm[i][j] = VZ; accc[i][j] = VZ; }
  gemm_tile<true>(gdH + (size_t)(m0 + rowS) * CD + k0 + ksw,
                  gdL + (size_t)(m0 + rowS) * CD + k0 + ksw,
                  owH + (size_t)(n0 + rowS) * CD + k0 + ksw,
                  owL + (size_t)(n0 + rowS) * CD + k0 + ksw,
                  (size_t)64 * CD, KS, lds, accm, accc);
  float* yp = y1p + (size_t)s * CN * CD;
  const int lane = t & 63, wave = t >> 6;
  const int wm = wave >> 1, wn = wave & 1;
  const int m16 = lane & 15, quad = lane >> 4;
#pragma unroll
  for (int sm = 0; sm < 2; ++sm)
#pragma unroll
    for (int sn = 0; sn < 4; ++sn)
#pragma unroll
      for (int r = 0; r < 4; ++r) {
        const int row = m0 + wm * 32 + sm * 16 + quad * 4 + r;
        const int col = n0 + wn * 64 + sn * 16 + m16;
        yp[(size_t)row * CD + col] = accm[sm][sn][r] + accc[sm][sn][r] * LO_INV;
      }
}

// -------------------------------------------------------------- layernorms

__device__ __forceinline__ void block_reduce2(float &s, float &ss, float* red) {
#pragma unroll
  for (int msk = 32; msk >= 1; msk >>= 1) {
    s += __shfl_xor(s, msk);
    ss += __shfl_xor(ss, msk);
  }
  const int wave = threadIdx.x >> 6, lane = threadIdx.x & 63;
  if (lane == 0) { red[wave] = s; red[4 + wave] = ss; }
  __syncthreads();
  s = red[0] + red[1] + red[2] + red[3];
  ss = red[4] + red[5] + red[6] + red[7];
}

// x = LN(src + y1p0 + y1p1)
__global__ __launch_bounds__(256) void k_ln1(
    const float* __restrict__ y1p, const float* __restrict__ srcp,
    const float* __restrict__ g, const float* __restrict__ bb,
    float* __restrict__ x, f16* __restrict__ xH) {
  __shared__ float red[8];
  const int n = blockIdx.x;
  const int t = threadIdx.x;
  const size_t off = (size_t)n * CD + t * 4;
  float4 v0 = *(const float4*)(y1p + off);
  float4 v1 = *(const float4*)(y1p + (size_t)CN * CD + off);
  float4 v2 = *(const float4*)(srcp + off);
  float a[4] = {v0.x + v1.x + v2.x, v0.y + v1.y + v2.y,
                v0.z + v1.z + v2.z, v0.w + v1.w + v2.w};
  float s = a[0] + a[1] + a[2] + a[3];
  float ss = a[0]*a[0] + a[1]*a[1] + a[2]*a[2] + a[3]*a[3];
  block_reduce2(s, ss, red);
  const float mean = s * (1.f / CD);
  const float var = ss * (1.f / CD) - mean * mean;
  const float rstd = rsqrtf(var + 1e-5f);
#pragma unroll
  for (int j = 0; j < 4; ++j) {
    const int d = t * 4 + j;
    const float val = (a[j] - mean) * rstd * g[d] + bb[d];
    x[(size_t)n * CD + d] = val;
    xH[(size_t)n * CD + d] = (f16)val;
  }
}

// out = LN2( 2*x + (zbp0+..+zbp3 + b2[e])*rs[e] )
__global__ __launch_bounds__(256) void k_ln2(
    const float* __restrict__ zbp, const float* __restrict__ x,
    const float* __restrict__ b2, const float* __restrict__ rsc,
    const int* __restrict__ chosen,
    const float* __restrict__ g, const float* __restrict__ bb,
    float* __restrict__ outp) {
  __shared__ float red[8];
  const int n = blockIdx.x;
  const int e = chosen[n];
  const float rs = rsc[e];
  const int t = threadIdx.x;
  const size_t off = (size_t)n * CD + t * 4;
  float4 p0 = *(const float4*)(zbp + off);
  float4 p1 = *(const float4*)(zbp + (size_t)CN * CD + off);
  float4 p2 = *(const float4*)(zbp + (size_t)2 * CN * CD + off);
  float4 p3 = *(const float4*)(zbp + (size_t)3 * CN * CD + off);
  float4 xv = *(const float4*)(x + off);
  float4 bv = *(const float4*)(b2 + (size_t)e * CD + t * 4);
  float a[4] = {2.f * xv.x + (p0.x + p1.x + p2.x + p3.x + bv.x) * rs,
                2.f * xv.y + (p0.y + p1.y + p2.y + p3.y + bv.y) * rs,
                2.f * xv.z + (p0.z + p1.z + p2.z + p3.z + bv.z) * rs,
                2.f * xv.w + (p0.w + p1.w + p2.w + p3.w + bv.w) * rs};
  float s = a[0] + a[1] + a[2] + a[3];
  float ss = a[0]*a[0] + a[1]*a[1] + a[2]*a[2] + a[3]*a[3];
  block_reduce2(s, ss, red);
  const float mean = s * (1.f / CD);
  const float var = ss * (1.f / CD) - mean * mean;
  const float rstd = rsqrtf(var + 1e-5f);
#pragma unroll
  for (int j = 0; j < 4; ++j) {
    const int d = t * 4 + j;
    outp[(size_t)n * CD + d] = (a[j] - mean) * rstd * g[d] + bb[d];
  }
}

// ------------------------------------------------------------------ routing

__global__ void k_zero_counts(int* counts) {
  if (threadIdx.x < CE) counts[threadIdx.x] = 0;
}

__global__ __launch_bounds__(256) void k_route(
    const float* __restrict__ x, const float* __restrict__ gw, const float* __restrict__ gb,
    int* __restrict__ chosen, int* __restrict__ counts, int* __restrict__ bucket) {
  const int wave = threadIdx.x >> 6, lane = threadIdx.x & 63;
  const int n = blockIdx.x * 4 + wave;
  const float* xr = x + (size_t)n * CD;
  float acc[CE];
#pragma unroll
  for (int e = 0; e < CE; ++e) acc[e] = 0.f;
  for (int j = 0; j < 16; ++j) {
    const int d = lane * 16 + j;
    const float xv = xr[d];
    const float* wr = gw + (size_t)d * CE;
#pragma unroll
    for (int e = 0; e < CE; ++e) acc[e] += xv * wr[e];
  }
#pragma unroll
  for (int msk = 32; msk >= 1; msk >>= 1) {
#pragma unroll
    for (int e = 0; e < CE; ++e) acc[e] += __shfl_xor(acc[e], msk);
  }
  if (lane == 0) {
    float best = -1e30f, second = -1e30f;
    int bi = 0, si = 0;
#pragma unroll
    for (int e = 0; e < CE; ++e) {
      const float L = acc[e] + gb[e];
      if (L > best) { second = best; si = bi; best = L; bi = e; }
      else if (L > second) { second = L; si = e; }
    }
    const int ch = bi > si ? bi : si;  // torch-loop semantics: max index wins
    chosen[n] = ch;
    const int pos = atomicAdd(&counts[ch], 1);
    bucket[ch * CN + pos] = n;
  }
}

// ------------------------------------------------------------------ MoE FFN

__global__ __launch_bounds__(256) void g_moe1(
    const f16* __restrict__ xH, const f16* __restrict__ w1t,
    const int* __restrict__ counts, const int* __restrict__ bucket,
    float* __restrict__ hbp /* [2][CN*CF] */) {
  const int ez = blockIdx.z;
  const int e = ez >> 1, s = ez & 1;
  const int cnt = counts[e];
  const int m0 = blockIdx.x * 64;
  if (m0 >= cnt) return;
  __shared__ f16 lds[6144];
  const int t = threadIdx.x;
  const int rowS = t >> 2;
  const int ksw = ((t & 3) ^ ((rowS >> 1) & 3)) * 8;
  const int k0 = s * KS;
  int ra = m0 + rowS; if (ra > cnt - 1) ra = cnt - 1;
  const int tokA = bucket[e * CN + ra];
  const int n0 = blockIdx.y * 128;
  const f32x4 VZ = {0.f, 0.f, 0.f, 0.f};
  f32x4 accm[2][4];
#pragma unroll
  for (int i = 0; i < 2; ++i)
#pragma unroll
    for (int j = 0; j < 4; ++j) accm[i][j] = VZ;
  gemm_tile<false>(xH + (size_t)tokA * CD + k0 + ksw, nullptr,
                   w1t + ((size_t)e * CF + n0 + rowS) * CD + k0 + ksw, nullptr,
                   (size_t)64 * CD, KS, lds, accm, accm);
  float* hp = hbp + (size_t)s * CN * CF;
  const int lane = t & 63, wave = t >> 6;
  const int wm = wave >> 1, wn = wave & 1;
  const int m16 = lane & 15, quad = lane >> 4;
#pragma unroll
  for (int sm = 0; sm < 2; ++sm)
#pragma unroll
    for (int sn = 0; sn < 4; ++sn)
#pragma unroll
      for (int r = 0; r < 4; ++r) {
        const int rr = m0 + wm * 32 + sm * 16 + quad * 4 + r;
        if (rr >= cnt) continue;
        const int tok = bucket[e * CN + rr];
        const int col = n0 + wn * 64 + sn * 16 + m16;
        hp[(size_t)tok * CF + col] = accm[sm][sn][r];
      }
}

// h2 = gelu(LN_e(hbp0+hbp1+b1[e]))
__global__ __launch_bounds__(256) void k_lngelu(
    const float* __restrict__ hbp, const int* __restrict__ chosen,
    const float* __restrict__ b1,
    const float* __restrict__ ln_g, const float* __restrict__ ln_b,
    f16* __restrict__ h2) {
  __shared__ float red[8];
  const int n = blockIdx.x;
  const int e = chosen[n];
  const int t = threadIdx.x;
  const size_t off = (size_t)n * CF + t * 8;
  float4 v0 = *(const float4*)(hbp + off);
  float4 v1 = *(const float4*)(hbp + off + 4);
  float4 u0 = *(const float4*)(hbp + (size_t)CN * CF + off);
  float4 u1 = *(const float4*)(hbp + (size_t)CN * CF + off + 4);
  float4 b0 = *(const float4*)(b1 + (size_t)e * CF + t * 8);
  float4 b1v = *(const float4*)(b1 + (size_t)e * CF + t * 8 + 4);
  float a[8] = {v0.x + u0.x + b0.x, v0.y + u0.y + b0.y,
                v0.z + u0.z + b0.z, v0.w + u0.w + b0.w,
                v1.x + u1.x + b1v.x, v1.y + u1.y + b1v.y,
                v1.z + u1.z + b1v.z, v1.w + u1.w + b1v.w};
  float s = 0.f, ss = 0.f;
#pragma unroll
  for (int j = 0; j < 8; ++j) { s += a[j]; ss += a[j] * a[j]; }
  block_reduce2(s, ss, red);
  const float mean = s * (1.f / CF);
  const float var = ss * (1.f / CF) - mean * mean;
  const float rstd = rsqrtf(var + 1e-5f);
  const float* g = ln_g + (size_t)e * CF;
  const float* bb = ln_b + (size_t)e * CF;
#pragma unroll
  for (int j = 0; j < 8; ++j) {
    const int d = t * 8 + j;
    const float val = (a[j] - mean) * rstd * g[d] + bb[d];
    const float gl = 0.5f * val * (1.f + erff(val * 0.70710678118654752f));
    h2[(size_t)n * CF + d] = (f16)gl;
  }
}

__global__ __launch_bounds__(256) void g_moe2(
    const f16* __restrict__ h2, const f16* __restrict__ w2t,
    const int* __restrict__ counts, const int* __restrict__ bucket,
    float* __restrict__ zbp /* [4][CN*CD] */) {
  const int ez = blockIdx.z;
  const int e = ez >> 2, s = ez & 3;
  const int cnt = counts[e];
  const int m0 = blockIdx.x * 64;
  if (m0 >= cnt) return;
  __shared__ f16 lds[6144];
  const int t = threadIdx.x;
  const int rowS = t >> 2;
  const int ksw = ((t & 3) ^ ((rowS >> 1) & 3)) * 8;
  const int k0 = s * KS;
  int ra = m0 + rowS; if (ra > cnt - 1) ra = cnt - 1;
  const int tokA = bucket[e * CN + ra];
  const int n0 = blockIdx.y * 128;
  const f32x4 VZ = {0.f, 0.f, 0.f, 0.f};
  f32x4 accm[2][4];
#pragma unroll
  for (int i = 0; i < 2; ++i)
#pragma unroll
    for (int j = 0; j < 4; ++j) accm[i][j] = VZ;
  gemm_tile<false>(h2 + (size_t)tokA * CF + k0 + ksw, nullptr,
                   w2t + ((size_t)e * CD + n0 + rowS) * CF + k0 + ksw, nullptr,
                   (size_t)64 * CF, KS, lds, accm, accm);
  float* zp = zbp + (size_t)s * CN * CD;
  const int lane = t & 63, wave = t >> 6;
  const int wm = wave >> 1, wn = wave & 1;
  const int m16 = lane & 15, quad = lane >> 4;
#pragma unroll
  for (int sm = 0; sm < 2; ++sm)
#pragma unroll
    for (int sn = 0; sn < 4; ++sn)
#pragma unroll
      for (int r = 0; r < 4; ++r) {
        const int rr = m0 + wm * 32 + sm * 16 + quad * 4 + r;
        if (rr >= cnt) continue;
        const int tok = bucket[e * CN + rr];
        const int col = n0 + wn * 64 + sn * 16 + m16;
        zp[(size_t)tok * CD + col] = accm[sm][sn][r];
      }
}

// ------------------------------------------------------------------- launch

extern "C" void kernel_launch(void* const* d_in, const int* in_sizes, int n_in,
                              void* d_out, int out_size, void* d_ws, size_t ws_size,
                              hipStream_t stream) {
  (void)in_sizes; (void)n_in; (void)out_size; (void)ws_size;
  const float* src        = (const float*)d_in[0];
  const float* q_w        = (const float*)d_in[1];
  const float* k_w        = (const float*)d_in[2];
  const float* v_w        = (const float*)d_in[3];
  const float* out_w      = (const float*)d_in[4];
  const float* gate_w     = (const float*)d_in[5];
  const float* gate_b     = (const float*)d_in[6];
  const float* scale_w    = (const float*)d_in[7];
  const float* n1_g       = (const float*)d_in[8];
  const float* n1_b       = (const float*)d_in[9];
  const float* n2_g       = (const float*)d_in[10];
  const float* n2_b       = (const float*)d_in[11];
  const float* moe_gate_w = (const float*)d_in[12];
  const float* moe_gate_b = (const float*)d_in[13];
  const float* w1         = (const float*)d_in[14];
  const float* b1         = (const float*)d_in[15];
  const float* ln_g       = (const float*)d_in[16];
  const float* ln_b       = (const float*)d_in[17];
  const float* w2         = (const float*)d_in[18];
  const float* b2         = (const float*)d_in[19];
  const float* res_scale  = (const float*)d_in[20];
  float* outp = (float*)d_out;

  char* p = (char*)d_ws;
  auto take = [&](size_t bytes) -> char* {
    char* r = p;
    p += (bytes + 255) & ~(size_t)255;
    return r;
  };
  f16* srcH = (f16*)take((size_t)CN * CD * 2);
  f16* srcL = (f16*)take((size_t)CN * CD * 2);
  f16* qwH = (f16*)take((size_t)CD * CD * 2);
  f16* qwL = (f16*)take((size_t)CD * CD * 2);
  f16* kwH = (f16*)take((size_t)CD * CD * 2);
  f16* kwL = (f16*)take((size_t)CD * CD * 2);
  f16* vwH = (f16*)take((size_t)CD * CD * 2);
  f16* vwL = (f16*)take((size_t)CD * CD * 2);
  f16* gwH = (f16*)take((size_t)CD * CD * 2);
  f16* gwL = (f16*)take((size_t)CD * CD * 2);
  f16* owH = (f16*)take((size_t)CD * CD * 2);
  f16* owL = (f16*)take((size_t)CD * CD * 2);
  f16* qH = (f16*)take((size_t)CBH * CS * CHD * 2);
  f16* qL = (f16*)take((size_t)CBH * CS * CHD * 2);
  f16* kH = (f16*)take((size_t)CBH * CS * CHD * 2);
  f16* kL = (f16*)take((size_t)CBH * CS * CHD * 2);
  f16* vTH = (f16*)take((size_t)CBH * CS * CHD * 2);
  f16* vTL = (f16*)take((size_t)CBH * CS * CHD * 2);
  f16* aoH = (f16*)take((size_t)CN * CD * 2);
  f16* aoL = (f16*)take((size_t)CN * CD * 2);
  f16* gdH = (f16*)take((size_t)CN * CD * 2);
  f16* gdL = (f16*)take((size_t)CN * CD * 2);
  float* x  = (float*)take((size_t)CN * CD * 4);
  f16* xH = (f16*)take((size_t)CN * CD * 2);
  int* counts = (int*)take(64);
  int* bucket = (int*)take((size_t)CE * CN * 4);
  int* chosen = (int*)take((size_t)CN * 4);
  f16* h2 = (f16*)take((size_t)CN * CF * 2);
  f16* w1t = (f16*)take((size_t)CE * CF * CD * 2);
  f16* w2t = (f16*)take((size_t)CE * CD * CF * 2);
  // time-shared 32 MB fp32 partial region: gpre[2] -> y1p[2] -> hbp[2] -> zbp[4]
  float* pbuf = (float*)take((size_t)4 * CN * CD * 4);

  // --- input conversion / weight transposition ---
  k_split_cvt<<<dim3(CN * CD / 4 / 256), 256, 0, stream>>>(src, srcH, srcL, CN * CD);
  dim3 tb(32, 8);
  k_transpose_split<<<dim3(CD / 32, CD / 32, 1), tb, 0, stream>>>(q_w, qwH, qwL, CD, CD);
  k_transpose_split<<<dim3(CD / 32, CD / 32, 1), tb, 0, stream>>>(k_w, kwH, kwL, CD, CD);
  k_transpose_split<<<dim3(CD / 32, CD / 32, 1), tb, 0, stream>>>(v_w, vwH, vwL, CD, CD);
  k_transpose_split<<<dim3(CD / 32, CD / 32, 1), tb, 0, stream>>>(gate_w, gwH, gwL, CD, CD);
  k_transpose_split<<<dim3(CD / 32, CD / 32, 1), tb, 0, stream>>>(out_w, owH, owL, CD, CD);
  k_transpose_split<<<dim3(CF / 32, CD / 32, CE), tb, 0, stream>>>(w1, w1t, nullptr, CD, CF);
  k_transpose_split<<<dim3(CD / 32, CF / 32, CE), tb, 0, stream>>>(w2, w2t, nullptr, CF, CD);

  // --- attention ---
  g_qkv<<<dim3(CN / 64, CD / 128, 3), 256, 0, stream>>>(
      srcH, srcL, qwH, qwL, kwH, kwL, vwH, vwL, qH, qL, kH, kL, vTH, vTL);
  k_fattn<<<dim3(CS / 64, CBH), 256, 0, stream>>>(
      qH, qL, kH, kL, vTH, vTL, scale_w, aoH, aoL);
  g_gate<<<dim3(CN / 64, CD / 128, 2), 256, 0, stream>>>(aoH, aoL, gwH, gwL, pbuf);
  k_gatemul<<<dim3(CN * CD / 4 / 256), 256, 0, stream>>>(pbuf, aoH, aoL, gate_b, gdH, gdL);
  g_outp<<<dim3(CN / 64, CD / 128, 2), 256, 0, stream>>>(gdH, gdL, owH, owL, pbuf);
  k_ln1<<<dim3(CN), 256, 0, stream>>>(pbuf, src, n1_g, n1_b, x, xH);

  // --- routing + MoE ---
  k_zero_counts<<<dim3(1), 64, 0, stream>>>(counts);
  k_route<<<dim3(CN / 4), 256, 0, stream>>>(x, moe_gate_w, moe_gate_b, chosen, counts, bucket);
  g_moe1<<<dim3(CN / 64, CF / 128, CE * 2), 256, 0, stream>>>(xH, w1t, counts, bucket, pbuf);
  k_lngelu<<<dim3(CN), 256, 0, stream>>>(pbuf, chosen, b1, ln_g, ln_b, h2);
  g_moe2<<<dim3(CN / 64, CD / 128, CE * 4), 256, 0, stream>>>(h2, w2t, counts, bucket, pbuf);
  k_ln2<<<dim3(CN), 256, 0, stream>>>(pbuf, x, b2, res_scale, chosen, n2_g, n2_b, outp);
}

// Round 5
// 618.545 us; speedup vs baseline: 1.2912x; 1.2912x over previous
//
#include <hip/hip_runtime.h>

// MemoAI fused block for MI355X (gfx950).
//  - fp16x2 split-precision MFMA (hi + 2^11-scaled lo) upstream of MoE routing
//  - plain fp16 MFMA for the expert FFN (post-routing)
//  - sum(softmax(top2)) == 1 -> moe weight multiplier is exactly 1
//  - only the chosen expert is computed (tokens bucketed by expert)
//  - R1: 64x128 LDS-staged GEMM core (global_load_lds width=16)
//  - R2: flash attention (online softmax, register scores), qscale fused
//  - R3: split-K on gate/outp/moe1/moe2 (partials folded into consumers)
//  - R4: MoE GEMMs get (a) tile-compacted grid via k_plan (fixes XCD
//    clustering: old grid's active blocks were all id%8<4 -> XCDs 4-7 idle)
//    and (b) single-barrier double-buffered K-loop (prefetch overlaps the
//    vmcnt drain with a full tile of ds_read+MFMA work).

typedef _Float16 f16;
typedef _Float16 f16x8 __attribute__((ext_vector_type(8)));
typedef _Float16 f16x4 __attribute__((ext_vector_type(4)));
typedef float f32x4 __attribute__((ext_vector_type(4)));

constexpr int CS  = 1024;  // seq len
constexpr int CD  = 1024;  // model dim
constexpr int CH  = 16;    // heads
constexpr int CHD = 64;    // head dim
constexpr int CF  = 2048;  // ffn dim
constexpr int CE  = 8;     // experts
constexpr int CN  = 2048;  // tokens = B*S
constexpr int CBH = 32;    // B*H
constexpr int KS  = 512;   // split-K slice width
constexpr int MAXT = 48;   // padded tile-table size (true max 39)

constexpr float LO_SCALE = 2048.f;       // 2^11: keeps lo-parts normal in fp16
constexpr float LO_INV   = 1.f / 2048.f;

#define MFMA16(a, b, c) __builtin_amdgcn_mfma_f32_16x16x32_f16((a), (b), (c), 0, 0, 0)

#define TO_GBL(p) ((const __attribute__((address_space(1))) void*)(p))
#define TO_LDS(p) ((__attribute__((address_space(3))) void*)(p))
#define GLD16(g, l) __builtin_amdgcn_global_load_lds(TO_GBL(g), TO_LDS(l), 16, 0, 0)

__device__ __forceinline__ void fsplit(float v, f16 &hi, f16 &lo) {
  hi = (f16)v;
  lo = (f16)((v - (float)hi) * LO_SCALE);
}

// ---------------------------------------------------------------- conversions

__global__ void k_split_cvt(const float* __restrict__ in, f16* __restrict__ oh,
                            f16* __restrict__ ol, int n) {
  int i = (blockIdx.x * blockDim.x + threadIdx.x) * 4;
  if (i >= n) return;
  float4 v = *(const float4*)(in + i);
  float a[4] = {v.x, v.y, v.z, v.w};
#pragma unroll
  for (int j = 0; j < 4; ++j) {
    f16 hi = (f16)a[j];
    oh[i + j] = hi;
    ol[i + j] = (f16)((a[j] - (float)hi) * LO_SCALE);
  }
}

// in: [Z][R][C] f32 -> outH(/outL scaled) : [Z][C][R] f16
__global__ void k_transpose_split(const float* __restrict__ in, f16* __restrict__ oh,
                                  f16* __restrict__ ol, int R, int C) {
  __shared__ float t[32][33];
  const int z = blockIdx.z;
  const float* src = in + (size_t)z * R * C;
  f16* dh = oh + (size_t)z * R * C;
  f16* dl = ol ? ol + (size_t)z * R * C : nullptr;
  const int c0 = blockIdx.x * 32, r0 = blockIdx.y * 32;
  const int tx = threadIdx.x, ty = threadIdx.y;
#pragma unroll
  for (int i = 0; i < 32; i += 8)
    t[ty + i][tx] = src[(size_t)(r0 + ty + i) * C + c0 + tx];
  __syncthreads();
#pragma unroll
  for (int i = 0; i < 32; i += 8) {
    float v = t[tx][ty + i];
    f16 hi = (f16)v;
    size_t idx = (size_t)(c0 + ty + i) * R + r0 + tx;
    dh[idx] = hi;
    if (dl) dl[idx] = (f16)((v - (float)hi) * LO_SCALE);
  }
}

// ------------------------------------------------------------- tiled GEMM core
// Block tile 64(M) x 128(N), BK=32, 4 waves (2x2), wave tile 32x64.

template <bool SPLIT>
__device__ __forceinline__ void gemm_tile(
    const f16* aH, const f16* aL, const f16* bH, const f16* bL,
    size_t bRowStride /* 64*ldb */, int K, f16* lds,
    f32x4 (&accm)[2][4], f32x4 (&accc)[2][4]) {
  f16* lAh = lds;                          // 64*32  = 2048 halves
  f16* lAl = lds + 2048;                   // (split only)
  f16* lBh = lds + (SPLIT ? 4096 : 2048);  // 128*32 = 4096 halves
  f16* lBl = lds + 8192;                   // (split only)
  const int t = threadIdx.x;
  const int lane = t & 63, wave = t >> 6;
  const int wm = wave >> 1, wn = wave & 1;
  const int m16 = lane & 15, quad = lane >> 4;
  int aoff[2], boff[4];
#pragma unroll
  for (int sm = 0; sm < 2; ++sm) {
    const int r = wm * 32 + sm * 16 + m16;
    aoff[sm] = r * 32 + ((quad ^ ((r >> 1) & 3)) * 8);
  }
#pragma unroll
  for (int sn = 0; sn < 4; ++sn) {
    const int r = wn * 64 + sn * 16 + m16;
    boff[sn] = r * 32 + ((quad ^ ((r >> 1) & 3)) * 8);
  }
  for (int k = 0; k < K; k += 32) {
    GLD16(aH, lAh + t * 8);
    GLD16(bH, lBh + t * 8);
    GLD16(bH + bRowStride, lBh + 2048 + t * 8);
    if constexpr (SPLIT) {
      GLD16(aL, lAl + t * 8);
      GLD16(bL, lBl + t * 8);
      GLD16(bL + bRowStride, lBl + 2048 + t * 8);
      aL += 32; bL += 32;
    }
    aH += 32; bH += 32;
    __syncthreads();  // drains vmcnt(0) -> staged data visible
    f16x8 af[2], alf[2], bf[4], blf[4];
#pragma unroll
    for (int sm = 0; sm < 2; ++sm) {
      af[sm] = *(const f16x8*)(lAh + aoff[sm]);
      if constexpr (SPLIT) alf[sm] = *(const f16x8*)(lAl + aoff[sm]);
    }
#pragma unroll
    for (int sn = 0; sn < 4; ++sn) {
      bf[sn] = *(const f16x8*)(lBh + boff[sn]);
      if constexpr (SPLIT) blf[sn] = *(const f16x8*)(lBl + boff[sn]);
    }
#pragma unroll
    for (int sm = 0; sm < 2; ++sm)
#pragma unroll
      for (int sn = 0; sn < 4; ++sn) {
        accm[sm][sn] = MFMA16(af[sm], bf[sn], accm[sm][sn]);
        if constexpr (SPLIT) {
          accc[sm][sn] = MFMA16(af[sm], blf[sn], accc[sm][sn]);
          accc[sm][sn] = MFMA16(alf[sm], bf[sn], accc[sm][sn]);
        }
      }
    __syncthreads();  // all waves done reading before next overwrite
  }
}

// Double-buffered single-barrier variant (non-split). LDS = 2 x 6144 halves.
// Prefetch for tile k+1 is issued right after the barrier; the vmcnt(0)
// drain at the NEXT barrier is then overlapped with this tile's ds/MFMA work.
// Safe with one barrier: reads of the overwritten buffer complete (into
// registers, lgkmcnt-drained) before the preceding barrier.
__device__ __forceinline__ void gemm_tile_db(
    const f16* aH, const f16* bH, size_t bRowStride, int K, f16* lds,
    f32x4 (&accm)[2][4]) {
  const int t = threadIdx.x;
  const int lane = t & 63, wave = t >> 6;
  const int wm = wave >> 1, wn = wave & 1;
  const int m16 = lane & 15, quad = lane >> 4;
  int aoff[2], boff[4];
#pragma unroll
  for (int sm = 0; sm < 2; ++sm) {
    const int r = wm * 32 + sm * 16 + m16;
    aoff[sm] = r * 32 + ((quad ^ ((r >> 1) & 3)) * 8);
  }
#pragma unroll
  for (int sn = 0; sn < 4; ++sn) {
    const int r = wn * 64 + sn * 16 + m16;
    boff[sn] = 2048 + r * 32 + ((quad ^ ((r >> 1) & 3)) * 8);
  }
  // prologue: stage tile 0 into buf 0
  GLD16(aH, lds + t * 8);
  GLD16(bH, lds + 2048 + t * 8);
  GLD16(bH + bRowStride, lds + 4096 + t * 8);
  aH += 32; bH += 32;
  int cur = 0;
  for (int k = 0; k < K; k += 32) {
    __syncthreads();  // buf[cur] staged (vmcnt0) + prev buffer fully consumed
    f16* buf = lds + cur * 6144;
    f16* nbuf = lds + (cur ^ 1) * 6144;
    if (k + 32 < K) {
      GLD16(aH, nbuf + t * 8);
      GLD16(bH, nbuf + 2048 + t * 8);
      GLD16(bH + bRowStride, nbuf + 4096 + t * 8);
      aH += 32; bH += 32;
    }
    f16x8 af[2], bf[4];
#pragma unroll
    for (int sm = 0; sm < 2; ++sm) af[sm] = *(const f16x8*)(buf + aoff[sm]);
#pragma unroll
    for (int sn = 0; sn < 4; ++sn) bf[sn] = *(const f16x8*)(buf + boff[sn]);
#pragma unroll
    for (int sm = 0; sm < 2; ++sm)
#pragma unroll
      for (int sn = 0; sn < 4; ++sn)
        accm[sm][sn] = MFMA16(af[sm], bf[sn], accm[sm][sn]);
    cur ^= 1;
  }
}

// ---------------------------------------------------------------- QKV

__global__ __launch_bounds__(256) void g_qkv(
    const f16* __restrict__ srcH, const f16* __restrict__ srcL,
    const f16* __restrict__ qwH, const f16* __restrict__ qwL,
    const f16* __restrict__ kwH, const f16* __restrict__ kwL,
    const f16* __restrict__ vwH, const f16* __restrict__ vwL,
    f16* __restrict__ qHo, f16* __restrict__ qLo,
    f16* __restrict__ kHo, f16* __restrict__ kLo,
    f16* __restrict__ vTH, f16* __restrict__ vTL) {
  __shared__ f16 lds[12288];
  const int z = blockIdx.z;
  const int m0 = blockIdx.x * 64, n0 = blockIdx.y * 128;
  const int t = threadIdx.x;
  const int rowS = t >> 2;
  const int ksw = ((t & 3) ^ ((rowS >> 1) & 3)) * 8;
  const f16* BH = (z == 0) ? qwH : (z == 1) ? kwH : vwH;
  const f16* BL = (z == 0) ? qwL : (z == 1) ? kwL : vwL;
  const f32x4 VZ = {0.f, 0.f, 0.f, 0.f};
  f32x4 accm[2][4], accc[2][4];
#pragma unroll
  for (int i = 0; i < 2; ++i)
#pragma unroll
    for (int j = 0; j < 4; ++j) { accm[i][j] = VZ; accc[i][j] = VZ; }
  gemm_tile<true>(srcH + (size_t)(m0 + rowS) * CD + ksw,
                  srcL + (size_t)(m0 + rowS) * CD + ksw,
                  BH + (size_t)(n0 + rowS) * CD + ksw,
                  BL + (size_t)(n0 + rowS) * CD + ksw,
                  (size_t)64 * CD, CD, lds, accm, accc);
  const int lane = t & 63, wave = t >> 6;
  const int wm = wave >> 1, wn = wave & 1;
  const int m16 = lane & 15, quad = lane >> 4;
#pragma unroll
  for (int sm = 0; sm < 2; ++sm)
#pragma unroll
    for (int sn = 0; sn < 4; ++sn)
#pragma unroll
      for (int r = 0; r < 4; ++r) {
        const int row = m0 + wm * 32 + sm * 16 + quad * 4 + r;  // token
        const int col = n0 + wn * 64 + sn * 16 + m16;           // d
        const float v = accm[sm][sn][r] + accc[sm][sn][r] * LO_INV;
        f16 hi, lo; fsplit(v, hi, lo);
        const int bb = row >> 10, ss = row & 1023;
        const int hh = col >> 6, hd = col & 63;
        if (z == 2) {  // v stored transposed: [b,h,hd,s]
          const size_t idx = ((size_t)((bb * CH + hh) * CHD + hd)) * CS + ss;
          vTH[idx] = hi; vTL[idx] = lo;
        } else {
          const size_t idx = ((size_t)((bb * CH + hh) * CS + ss)) * CHD + hd;
          if (z == 0) { qHo[idx] = hi; qLo[idx] = lo; }
          else        { kHo[idx] = hi; kLo[idx] = lo; }
        }
      }
}

// ------------------------------------------------------- flash attention

__device__ __forceinline__ int pswz(int q, int k) {
  return q * 64 + ((((k >> 2) ^ q) & 15) << 2) + (k & 3);
}

__global__ __launch_bounds__(256) void k_fattn(
    const f16* __restrict__ qH_, const f16* __restrict__ qL_,
    const f16* __restrict__ kH_, const f16* __restrict__ kL_,
    const f16* __restrict__ vTH_, const f16* __restrict__ vTL_,
    const float* __restrict__ scale_w,
    f16* __restrict__ aoH, f16* __restrict__ aoL) {
  __shared__ float psc[4 * 1024];  // 4 waves x (16x64) P tile, swizzled
  const int bh = blockIdx.y;
  const int b = bh >> 4, h = bh & 15;
  const int lane = threadIdx.x & 63, wave = threadIdx.x >> 6;
  const int m16 = lane & 15, quad = lane >> 4;
  const int q0 = blockIdx.x * 64 + wave * 16;  // this wave's q rows
  float* P = psc + wave * 1024;
  const f32x4 VZ = {0.f, 0.f, 0.f, 0.f};

  const f16* qrh = qH_ + ((size_t)bh * CS + q0 + m16) * CHD + quad * 8;
  const f16* qrl = qL_ + ((size_t)bh * CS + q0 + m16) * CHD + quad * 8;
  f16x8 a0h = *(const f16x8*)(qrh);
  f16x8 a1h = *(const f16x8*)(qrh + 32);
  f16x8 a0l = *(const f16x8*)(qrl);
  f16x8 a1l = *(const f16x8*)(qrl + 32);

  // fused dynamic scale: row factor = 2*sigmoid(q . scale_w[h]) / sqrt(64)
  float dot = 0.f;
  {
    const float* sw = scale_w + h * CHD + quad * 8;
    float4 s0 = *(const float4*)(sw);
    float4 s1 = *(const float4*)(sw + 4);
    float4 s2 = *(const float4*)(sw + 32);
    float4 s3 = *(const float4*)(sw + 36);
    float sv[16] = {s0.x, s0.y, s0.z, s0.w, s1.x, s1.y, s1.z, s1.w,
                    s2.x, s2.y, s2.z, s2.w, s3.x, s3.y, s3.z, s3.w};
#pragma unroll
    for (int j = 0; j < 8; ++j) {
      dot += ((float)a0h[j] + (float)a0l[j] * LO_INV) * sv[j];
      dot += ((float)a1h[j] + (float)a1l[j] * LO_INV) * sv[8 + j];
    }
    dot += __shfl_xor(dot, 16);
    dot += __shfl_xor(dot, 32);
  }
  const float qsv = 2.f / (1.f + __expf(-dot));  // for row q0+m16
  float qsr[4];
#pragma unroll
  for (int r = 0; r < 4; ++r) qsr[r] = __shfl(qsv, quad * 4 + r) * 0.125f;

  f32x4 accm[4], accc[4];  // out accumulator: 4 hd-tiles, C-layout
#pragma unroll
  for (int t = 0; t < 4; ++t) { accm[t] = VZ; accc[t] = VZ; }
  float mrun[4], lrun[4];
#pragma unroll
  for (int r = 0; r < 4; ++r) { mrun[r] = -1e30f; lrun[r] = 0.f; }

  for (int kc = 0; kc < CS; kc += 64) {
    f32x4 st[4];
#pragma unroll
    for (int t = 0; t < 4; ++t) {
      const f16* krh = kH_ + ((size_t)bh * CS + kc + t * 16 + m16) * CHD + quad * 8;
      const f16* krl = kL_ + ((size_t)bh * CS + kc + t * 16 + m16) * CHD + quad * 8;
      f16x8 b0h = *(const f16x8*)(krh);
      f16x8 b1h = *(const f16x8*)(krh + 32);
      f16x8 b0l = *(const f16x8*)(krl);
      f16x8 b1l = *(const f16x8*)(krl + 32);
      f32x4 am = VZ, ac = VZ;
      am = MFMA16(a0h, b0h, am); am = MFMA16(a1h, b1h, am);
      ac = MFMA16(a0h, b0l, ac); ac = MFMA16(a0l, b0h, ac);
      ac = MFMA16(a1h, b1l, ac); ac = MFMA16(a1l, b1h, ac);
#pragma unroll
      for (int r = 0; r < 4; ++r)
        st[t][r] = (am[r] + ac[r] * LO_INV) * qsr[r];
    }
    float alpha[4];
#pragma unroll
    for (int r = 0; r < 4; ++r) {
      float mx = fmaxf(fmaxf(st[0][r], st[1][r]), fmaxf(st[2][r], st[3][r]));
#pragma unroll
      for (int msk = 8; msk >= 1; msk >>= 1) mx = fmaxf(mx, __shfl_xor(mx, msk));
      const float mnew = fmaxf(mrun[r], mx);
      alpha[r] = __expf(mrun[r] - mnew);
      mrun[r] = mnew;
    }
    float rs[4] = {0.f, 0.f, 0.f, 0.f};
#pragma unroll
    for (int t = 0; t < 4; ++t)
#pragma unroll
      for (int r = 0; r < 4; ++r) {
        const float e = __expf(st[t][r] - mrun[r]);
        rs[r] += e;
        P[pswz(quad * 4 + r, t * 16 + m16)] = e;
      }
#pragma unroll
    for (int r = 0; r < 4; ++r) {
#pragma unroll
      for (int msk = 8; msk >= 1; msk >>= 1) rs[r] += __shfl_xor(rs[r], msk);
      lrun[r] = lrun[r] * alpha[r] + rs[r];
#pragma unroll
      for (int t = 0; t < 4; ++t) { accm[t][r] *= alpha[r]; accc[t][r] *= alpha[r]; }
    }
    f16x8 pah[2], pal[2];
#pragma unroll
    for (int c = 0; c < 2; ++c) {
      const int k0 = c * 32 + quad * 8;
      float4 p0 = *(const float4*)(P + pswz(m16, k0));
      float4 p1 = *(const float4*)(P + pswz(m16, k0 + 4));
      float pv[8] = {p0.x, p0.y, p0.z, p0.w, p1.x, p1.y, p1.z, p1.w};
#pragma unroll
      for (int j = 0; j < 8; ++j) {
        f16 hi = (f16)pv[j];
        pah[c][j] = hi;
        pal[c][j] = (f16)((pv[j] - (float)hi) * LO_SCALE);
      }
    }
#pragma unroll
    for (int t = 0; t < 4; ++t) {
      const f16* vrh = vTH_ + ((size_t)bh * CHD + t * 16 + m16) * CS + kc + quad * 8;
      const f16* vrl = vTL_ + ((size_t)bh * CHD + t * 16 + m16) * CS + kc + quad * 8;
#pragma unroll
      for (int c = 0; c < 2; ++c) {
        f16x8 vbh = *(const f16x8*)(vrh + c * 32);
        f16x8 vbl = *(const f16x8*)(vrl + c * 32);
        accm[t] = MFMA16(pah[c], vbh, accm[t]);
        accc[t] = MFMA16(pah[c], vbl, accc[t]);
        accc[t] = MFMA16(pal[c], vbh, accc[t]);
      }
    }
  }
#pragma unroll
  for (int t = 0; t < 4; ++t)
#pragma unroll
    for (int r = 0; r < 4; ++r) {
      const int row = q0 + quad * 4 + r;
      const float v = (accm[t][r] + accc[t][r] * LO_INV) / lrun[r];
      f16 hi, lo; fsplit(v, hi, lo);
      const size_t idx = ((size_t)(b * CS + row)) * CD + h * CHD + t * 16 + m16;
      aoH[idx] = hi; aoL[idx] = lo;
    }
}

// ------------------------------------------- gate / out (split-K partials)

__global__ __launch_bounds__(256) void g_gate(
    const f16* __restrict__ aoH, const f16* __restrict__ aoL,
    const f16* __restrict__ gwH, const f16* __restrict__ gwL,
    float* __restrict__ gpre /* [2][CN*CD] */) {
  __shared__ f16 lds[12288];
  const int m0 = blockIdx.x * 64, n0 = blockIdx.y * 128, s = blockIdx.z;
  const int t = threadIdx.x;
  const int rowS = t >> 2;
  const int ksw = ((t & 3) ^ ((rowS >> 1) & 3)) * 8;
  const int k0 = s * KS;
  const f32x4 VZ = {0.f, 0.f, 0.f, 0.f};
  f32x4 accm[2][4], accc[2][4];
#pragma unroll
  for (int i = 0; i < 2; ++i)
#pragma unroll
    for (int j = 0; j < 4; ++j) { accm[i][j] = VZ; accc[i][j] = VZ; }
  gemm_tile<true>(aoH + (size_t)(m0 + rowS) * CD + k0 + ksw,
                  aoL + (size_t)(m0 + rowS) * CD + k0 + ksw,
                  gwH + (size_t)(n0 + rowS) * CD + k0 + ksw,
                  gwL + (size_t)(n0 + rowS) * CD + k0 + ksw,
                  (size_t)64 * CD, KS, lds, accm, accc);
  float* gp = gpre + (size_t)s * CN * CD;
  const int lane = t & 63, wave = t >> 6;
  const int wm = wave >> 1, wn = wave & 1;
  const int m16 = lane & 15, quad = lane >> 4;
#pragma unroll
  for (int sm = 0; sm < 2; ++sm)
#pragma unroll
    for (int sn = 0; sn < 4; ++sn)
#pragma unroll
      for (int r = 0; r < 4; ++r) {
        const int row = m0 + wm * 32 + sm * 16 + quad * 4 + r;
        const int col = n0 + wn * 64 + sn * 16 + m16;
        gp[(size_t)row * CD + col] = accm[sm][sn][r] + accc[sm][sn][r] * LO_INV;
      }
}

// gd = fsplit(ao * sigmoid(gpre0+gpre1+gate_b))
__global__ __launch_bounds__(256) void k_gatemul(
    const float* __restrict__ gpre, const f16* __restrict__ aoH,
    const f16* __restrict__ aoL, const float* __restrict__ gate_b,
    f16* __restrict__ gdH, f16* __restrict__ gdL) {
  const int i = (blockIdx.x * 256 + threadIdx.x) * 4;
  float4 p0 = *(const float4*)(gpre + i);
  float4 p1 = *(const float4*)(gpre + (size_t)CN * CD + i);
  float4 gb = *(const float4*)(gate_b + (i & (CD - 1)));
  f16x4 ah = *(const f16x4*)(aoH + i);
  f16x4 al = *(const f16x4*)(aoL + i);
  float pre[4] = {p0.x + p1.x + gb.x, p0.y + p1.y + gb.y,
                  p0.z + p1.z + gb.z, p0.w + p1.w + gb.w};
  f16x4 oh, ol;
#pragma unroll
  for (int j = 0; j < 4; ++j) {
    const float g = 1.f / (1.f + __expf(-pre[j]));
    const float ov = ((float)ah[j] + (float)al[j] * LO_INV) * g;
    f16 hi, lo; fsplit(ov, hi, lo);
    oh[j] = hi; ol[j] = lo;
  }
  *(f16x4*)(gdH + i) = oh;
  *(f16x4*)(gdL + i) = ol;
}

__global__ __launch_bounds__(256) void g_outp(
    const f16* __restrict__ gdH, const f16* __restrict__ gdL,
    const f16* __restrict__ owH, const f16* __restrict__ owL,
    float* __restrict__ y1p /* [2][CN*CD] */) {
  __shared__ f16 lds[12288];
  const int m0 = blockIdx.x * 64, n0 = blockIdx.y * 128, s = blockIdx.z;
  const int t = threadIdx.x;
  const int rowS = t >> 2;
  const int ksw = ((t & 3) ^ ((rowS >> 1) & 3)) * 8;
  const int k0 = s * KS;
  const f32x4 VZ = {0.f, 0.f, 0.f, 0.f};
  f32x4 accm[2][4], accc[2][4];
#pragma unroll
  for (int i = 0; i < 2; ++i)
#pragma unroll
    for (int j = 0; j < 4; ++j) { accm[i][j] = VZ; accc[i][j] = VZ; }
  gemm_tile<true>(gdH + (size_t)(m0 + rowS) * CD + k0 + ksw,
                  gdL + (size_t)(m0 + rowS) * CD + k0 + ksw,
                  owH + (size_t)(n0 + rowS) * CD + k0 + ksw,
                  owL + (size_t)(n0 + rowS) * CD + k0 + ksw,
                  (size_t)64 * CD, KS, lds, accm, accc);
  float* yp = y1p + (size_t)s * CN * CD;
  const int lane = t & 63, wave = t >> 6;
  const int wm = wave >> 1, wn = wave & 1;
  const int m16 = lane & 15, quad = lane >> 4;
#pragma unroll
  for (int sm = 0; sm < 2; ++sm)
#pragma unroll
    for (int sn = 0; sn < 4; ++sn)
#pragma unroll
      for (int r = 0; r < 4; ++r) {
        const int row = m0 + wm * 32 + sm * 16 + quad * 4 + r;
        const int col = n0 + wn * 64 + sn * 16 + m16;
        yp[(size_t)row * CD + col] = accm[sm][sn][r] + accc[sm][sn][r] * LO_INV;
      }
}

// -------------------------------------------------------------- layernorms

__device__ __forceinline__ void block_reduce2(float &s, float &ss, float* red) {
#pragma unroll
  for (int msk = 32; msk >= 1; msk >>= 1) {
    s += __shfl_xor(s, msk);
    ss += __shfl_xor(ss, msk);
  }
  const int wave = threadIdx.x >> 6, lane = threadIdx.x & 63;
  if (lane == 0) { red[wave] = s; red[4 + wave] = ss; }
  __syncthreads();
  s = red[0] + red[1] + red[2] + red[3];
  ss = red[4] + red[5] + red[6] + red[7];
}

// x = LN(src + y1p0 + y1p1)
__global__ __launch_bounds__(256) void k_ln1(
    const float* __restrict__ y1p, const float* __restrict__ srcp,
    const float* __restrict__ g, const float* __restrict__ bb,
    float* __restrict__ x, f16* __restrict__ xH) {
  __shared__ float red[8];
  const int n = blockIdx.x;
  const int t = threadIdx.x;
  const size_t off = (size_t)n * CD + t * 4;
  float4 v0 = *(const float4*)(y1p + off);
  float4 v1 = *(const float4*)(y1p + (size_t)CN * CD + off);
  float4 v2 = *(const float4*)(srcp + off);
  float a[4] = {v0.x + v1.x + v2.x, v0.y + v1.y + v2.y,
                v0.z + v1.z + v2.z, v0.w + v1.w + v2.w};
  float s = a[0] + a[1] + a[2] + a[3];
  float ss = a[0]*a[0] + a[1]*a[1] + a[2]*a[2] + a[3]*a[3];
  block_reduce2(s, ss, red);
  const float mean = s * (1.f / CD);
  const float var = ss * (1.f / CD) - mean * mean;
  const float rstd = rsqrtf(var + 1e-5f);
#pragma unroll
  for (int j = 0; j < 4; ++j) {
    const int d = t * 4 + j;
    const float val = (a[j] - mean) * rstd * g[d] + bb[d];
    x[(size_t)n * CD + d] = val;
    xH[(size_t)n * CD + d] = (f16)val;
  }
}

// out = LN2( 2*x + (zbp0+..+zbp3 + b2[e])*rs[e] )
__global__ __launch_bounds__(256) void k_ln2(
    const float* __restrict__ zbp, const float* __restrict__ x,
    const float* __restrict__ b2, const float* __restrict__ rsc,
    const int* __restrict__ chosen,
    const float* __restrict__ g, const float* __restrict__ bb,
    float* __restrict__ outp) {
  __shared__ float red[8];
  const int n = blockIdx.x;
  const int e = chosen[n];
  const float rs = rsc[e];
  const int t = threadIdx.x;
  const size_t off = (size_t)n * CD + t * 4;
  float4 p0 = *(const float4*)(zbp + off);
  float4 p1 = *(const float4*)(zbp + (size_t)CN * CD + off);
  float4 p2 = *(const float4*)(zbp + (size_t)2 * CN * CD + off);
  float4 p3 = *(const float4*)(zbp + (size_t)3 * CN * CD + off);
  float4 xv = *(const float4*)(x + off);
  float4 bv = *(const float4*)(b2 + (size_t)e * CD + t * 4);
  float a[4] = {2.f * xv.x + (p0.x + p1.x + p2.x + p3.x + bv.x) * rs,
                2.f * xv.y + (p0.y + p1.y + p2.y + p3.y + bv.y) * rs,
                2.f * xv.z + (p0.z + p1.z + p2.z + p3.z + bv.z) * rs,
                2.f * xv.w + (p0.w + p1.w + p2.w + p3.w + bv.w) * rs};
  float s = a[0] + a[1] + a[2] + a[3];
  float ss = a[0]*a[0] + a[1]*a[1] + a[2]*a[2] + a[3]*a[3];
  block_reduce2(s, ss, red);
  const float mean = s * (1.f / CD);
  const float var = ss * (1.f / CD) - mean * mean;
  const float rstd = rsqrtf(var + 1e-5f);
#pragma unroll
  for (int j = 0; j < 4; ++j) {
    const int d = t * 4 + j;
    outp[(size_t)n * CD + d] = (a[j] - mean) * rstd * g[d] + bb[d];
  }
}

// ------------------------------------------------------------------ routing

__global__ void k_zero_counts(int* counts) {
  if (threadIdx.x < CE) counts[threadIdx.x] = 0;
}

__global__ __launch_bounds__(256) void k_route(
    const float* __restrict__ x, const float* __restrict__ gw, const float* __restrict__ gb,
    int* __restrict__ chosen, int* __restrict__ counts, int* __restrict__ bucket) {
  const int wave = threadIdx.x >> 6, lane = threadIdx.x & 63;
  const int n = blockIdx.x * 4 + wave;
  const float* xr = x + (size_t)n * CD;
  float acc[CE];
#pragma unroll
  for (int e = 0; e < CE; ++e) acc[e] = 0.f;
  for (int j = 0; j < 16; ++j) {
    const int d = lane * 16 + j;
    const float xv = xr[d];
    const float* wr = gw + (size_t)d * CE;
#pragma unroll
    for (int e = 0; e < CE; ++e) acc[e] += xv * wr[e];
  }
#pragma unroll
  for (int msk = 32; msk >= 1; msk >>= 1) {
#pragma unroll
    for (int e = 0; e < CE; ++e) acc[e] += __shfl_xor(acc[e], msk);
  }
  if (lane == 0) {
    float best = -1e30f, second = -1e30f;
    int bi = 0, si = 0;
#pragma unroll
    for (int e = 0; e < CE; ++e) {
      const float L = acc[e] + gb[e];
      if (L > best) { second = best; si = bi; best = L; bi = e; }
      else if (L > second) { second = L; si = e; }
    }
    const int ch = bi > si ? bi : si;  // torch-loop semantics: max index wins
    chosen[n] = ch;
    const int pos = atomicAdd(&counts[ch], 1);
    bucket[ch * CN + pos] = n;
  }
}

// build dense tile table: (expert, m0) for every 64-row tile of every expert
__global__ void k_plan(const int* __restrict__ counts, int* __restrict__ tiles) {
  if (threadIdx.x == 0) {
    int n = 0;
    for (int e = 0; e < CE; ++e) {
      const int c = counts[e];
      for (int m0 = 0; m0 < c; m0 += 64) { tiles[2 * n] = e; tiles[2 * n + 1] = m0; ++n; }
    }
    for (; n < MAXT; ++n) { tiles[2 * n] = -1; tiles[2 * n + 1] = 0; }
  }
}

// ------------------------------------------------------------------ MoE FFN

__global__ __launch_bounds__(256) void g_moe1(
    const f16* __restrict__ xH, const f16* __restrict__ w1t,
    const int* __restrict__ counts, const int* __restrict__ bucket,
    const int* __restrict__ tiles, float* __restrict__ hbp /* [2][CN*CF] */) {
  const int e = tiles[2 * blockIdx.x];
  if (e < 0) return;
  const int m0 = tiles[2 * blockIdx.x + 1];
  const int cnt = counts[e];
  const int s = blockIdx.z;
  __shared__ f16 lds[12288];  // 2 x 6144 (dbuf)
  const int t = threadIdx.x;
  const int rowS = t >> 2;
  const int ksw = ((t & 3) ^ ((rowS >> 1) & 3)) * 8;
  const int k0 = s * KS;
  int ra = m0 + rowS; if (ra > cnt - 1) ra = cnt - 1;
  const int tokA = bucket[e * CN + ra];
  const int n0 = blockIdx.y * 128;
  const f32x4 VZ = {0.f, 0.f, 0.f, 0.f};
  f32x4 accm[2][4];
#pragma unroll
  for (int i = 0; i < 2; ++i)
#pragma unroll
    for (int j = 0; j < 4; ++j) accm[i][j] = VZ;
  gemm_tile_db(xH + (size_t)tokA * CD + k0 + ksw,
               w1t + ((size_t)e * CF + n0 + rowS) * CD + k0 + ksw,
               (size_t)64 * CD, KS, lds, accm);
  float* hp = hbp + (size_t)s * CN * CF;
  const int lane = t & 63, wave = t >> 6;
  const int wm = wave >> 1, wn = wave & 1;
  const int m16 = lane & 15, quad = lane >> 4;
#pragma unroll
  for (int sm = 0; sm < 2; ++sm)
#pragma unroll
    for (int sn = 0; sn < 4; ++sn)
#pragma unroll
      for (int r = 0; r < 4; ++r) {
        const int rr = m0 + wm * 32 + sm * 16 + quad * 4 + r;
        if (rr >= cnt) continue;
        const int tok = bucket[e * CN + rr];
        const int col = n0 + wn * 64 + sn * 16 + m16;
        hp[(size_t)tok * CF + col] = accm[sm][sn][r];
      }
}

// h2 = gelu(LN_e(hbp0+hbp1+b1[e]))
__global__ __launch_bounds__(256) void k_lngelu(
    const float* __restrict__ hbp, const int* __restrict__ chosen,
    const float* __restrict__ b1,
    const float* __restrict__ ln_g, const float* __restrict__ ln_b,
    f16* __restrict__ h2) {
  __shared__ float red[8];
  const int n = blockIdx.x;
  const int e = chosen[n];
  const int t = threadIdx.x;
  const size_t off = (size_t)n * CF + t * 8;
  float4 v0 = *(const float4*)(hbp + off);
  float4 v1 = *(const float4*)(hbp + off + 4);
  float4 u0 = *(const float4*)(hbp + (size_t)CN * CF + off);
  float4 u1 = *(const float4*)(hbp + (size_t)CN * CF + off + 4);
  float4 b0 = *(const float4*)(b1 + (size_t)e * CF + t * 8);
  float4 b1v = *(const float4*)(b1 + (size_t)e * CF + t * 8 + 4);
  float a[8] = {v0.x + u0.x + b0.x, v0.y + u0.y + b0.y,
                v0.z + u0.z + b0.z, v0.w + u0.w + b0.w,
                v1.x + u1.x + b1v.x, v1.y + u1.y + b1v.y,
                v1.z + u1.z + b1v.z, v1.w + u1.w + b1v.w};
  float s = 0.f, ss = 0.f;
#pragma unroll
  for (int j = 0; j < 8; ++j) { s += a[j]; ss += a[j] * a[j]; }
  block_reduce2(s, ss, red);
  const float mean = s * (1.f / CF);
  const float var = ss * (1.f / CF) - mean * mean;
  const float rstd = rsqrtf(var + 1e-5f);
  const float* g = ln_g + (size_t)e * CF;
  const float* bb = ln_b + (size_t)e * CF;
#pragma unroll
  for (int j = 0; j < 8; ++j) {
    const int d = t * 8 + j;
    const float val = (a[j] - mean) * rstd * g[d] + bb[d];
    const float gl = 0.5f * val * (1.f + erff(val * 0.70710678118654752f));
    h2[(size_t)n * CF + d] = (f16)gl;
  }
}

__global__ __launch_bounds__(256) void g_moe2(
    const f16* __restrict__ h2, const f16* __restrict__ w2t,
    const int* __restrict__ counts, const int* __restrict__ bucket,
    const int* __restrict__ tiles, float* __restrict__ zbp /* [4][CN*CD] */) {
  const int e = tiles[2 * blockIdx.x];
  if (e < 0) return;
  const int m0 = tiles[2 * blockIdx.x + 1];
  const int cnt = counts[e];
  const int s = blockIdx.z;
  __shared__ f16 lds[12288];  // 2 x 6144 (dbuf)
  const int t = threadIdx.x;
  const int rowS = t >> 2;
  const int ksw = ((t & 3) ^ ((rowS >> 1) & 3)) * 8;
  const int k0 = s * KS;
  int ra = m0 + rowS; if (ra > cnt - 1) ra = cnt - 1;
  const int tokA = bucket[e * CN + ra];
  const int n0 = blockIdx.y * 128;
  const f32x4 VZ = {0.f, 0.f, 0.f, 0.f};
  f32x4 accm[2][4];
#pragma unroll
  for (int i = 0; i < 2; ++i)
#pragma unroll
    for (int j = 0; j < 4; ++j) accm[i][j] = VZ;
  gemm_tile_db(h2 + (size_t)tokA * CF + k0 + ksw,
               w2t + ((size_t)e * CD + n0 + rowS) * CF + k0 + ksw,
               (size_t)64 * CF, KS, lds, accm);
  float* zp = zbp + (size_t)s * CN * CD;
  const int lane = t & 63, wave = t >> 6;
  const int wm = wave >> 1, wn = wave & 1;
  const int m16 = lane & 15, quad = lane >> 4;
#pragma unroll
  for (int sm = 0; sm < 2; ++sm)
#pragma unroll
    for (int sn = 0; sn < 4; ++sn)
#pragma unroll
      for (int r = 0; r < 4; ++r) {
        const int rr = m0 + wm * 32 + sm * 16 + quad * 4 + r;
        if (rr >= cnt) continue;
        const int tok = bucket[e * CN + rr];
        const int col = n0 + wn * 64 + sn * 16 + m16;
        zp[(size_t)tok * CD + col] = accm[sm][sn][r];
      }
}

// ------------------------------------------------------------------- launch

extern "C" void kernel_launch(void* const* d_in, const int* in_sizes, int n_in,
                              void* d_out, int out_size, void* d_ws, size_t ws_size,
                              hipStream_t stream) {
  (void)in_sizes; (void)n_in; (void)out_size; (void)ws_size;
  const float* src        = (const float*)d_in[0];
  const float* q_w        = (const float*)d_in[1];
  const float* k_w        = (const float*)d_in[2];
  const float* v_w        = (const float*)d_in[3];
  const float* out_w      = (const float*)d_in[4];
  const float* gate_w     = (const float*)d_in[5];
  const float* gate_b     = (const float*)d_in[6];
  const float* scale_w    = (const float*)d_in[7];
  const float* n1_g       = (const float*)d_in[8];
  const float* n1_b       = (const float*)d_in[9];
  const float* n2_g       = (const float*)d_in[10];
  const float* n2_b       = (const float*)d_in[11];
  const float* moe_gate_w = (const float*)d_in[12];
  const float* moe_gate_b = (const float*)d_in[13];
  const float* w1         = (const float*)d_in[14];
  const float* b1         = (const float*)d_in[15];
  const float* ln_g       = (const float*)d_in[16];
  const float* ln_b       = (const float*)d_in[17];
  const float* w2         = (const float*)d_in[18];
  const float* b2         = (const float*)d_in[19];
  const float* res_scale  = (const float*)d_in[20];
  float* outp = (float*)d_out;

  char* p = (char*)d_ws;
  auto take = [&](size_t bytes) -> char* {
    char* r = p;
    p += (bytes + 255) & ~(size_t)255;
    return r;
  };
  f16* srcH = (f16*)take((size_t)CN * CD * 2);
  f16* srcL = (f16*)take((size_t)CN * CD * 2);
  f16* qwH = (f16*)take((size_t)CD * CD * 2);
  f16* qwL = (f16*)take((size_t)CD * CD * 2);
  f16* kwH = (f16*)take((size_t)CD * CD * 2);
  f16* kwL = (f16*)take((size_t)CD * CD * 2);
  f16* vwH = (f16*)take((size_t)CD * CD * 2);
  f16* vwL = (f16*)take((size_t)CD * CD * 2);
  f16* gwH = (f16*)take((size_t)CD * CD * 2);
  f16* gwL = (f16*)take((size_t)CD * CD * 2);
  f16* owH = (f16*)take((size_t)CD * CD * 2);
  f16* owL = (f16*)take((size_t)CD * CD * 2);
  f16* qH = (f16*)take((size_t)CBH * CS * CHD * 2);
  f16* qL = (f16*)take((size_t)CBH * CS * CHD * 2);
  f16* kH = (f16*)take((size_t)CBH * CS * CHD * 2);
  f16* kL = (f16*)take((size_t)CBH * CS * CHD * 2);
  f16* vTH = (f16*)take((size_t)CBH * CS * CHD * 2);
  f16* vTL = (f16*)take((size_t)CBH * CS * CHD * 2);
  f16* aoH = (f16*)take((size_t)CN * CD * 2);
  f16* aoL = (f16*)take((size_t)CN * CD * 2);
  f16* gdH = (f16*)take((size_t)CN * CD * 2);
  f16* gdL = (f16*)take((size_t)CN * CD * 2);
  float* x  = (float*)take((size_t)CN * CD * 4);
  f16* xH = (f16*)take((size_t)CN * CD * 2);
  int* counts = (int*)take(64);
  int* bucket = (int*)take((size_t)CE * CN * 4);
  int* chosen = (int*)take((size_t)CN * 4);
  int* tiles = (int*)take((size_t)MAXT * 2 * 4);
  f16* h2 = (f16*)take((size_t)CN * CF * 2);
  f16* w1t = (f16*)take((size_t)CE * CF * CD * 2);
  f16* w2t = (f16*)take((size_t)CE * CD * CF * 2);
  // time-shared 32 MB fp32 partial region: gpre[2] -> y1p[2] -> hbp[2] -> zbp[4]
  float* pbuf = (float*)take((size_t)4 * CN * CD * 4);

  // --- input conversion / weight transposition ---
  k_split_cvt<<<dim3(CN * CD / 4 / 256), 256, 0, stream>>>(src, srcH, srcL, CN * CD);
  dim3 tb(32, 8);
  k_transpose_split<<<dim3(CD / 32, CD / 32, 1), tb, 0, stream>>>(q_w, qwH, qwL, CD, CD);
  k_transpose_split<<<dim3(CD / 32, CD / 32, 1), tb, 0, stream>>>(k_w, kwH, kwL, CD, CD);
  k_transpose_split<<<dim3(CD / 32, CD / 32, 1), tb, 0, stream>>>(v_w, vwH, vwL, CD, CD);
  k_transpose_split<<<dim3(CD / 32, CD / 32, 1), tb, 0, stream>>>(gate_w, gwH, gwL, CD, CD);
  k_transpose_split<<<dim3(CD / 32, CD / 32, 1), tb, 0, stream>>>(out_w, owH, owL, CD, CD);
  k_transpose_split<<<dim3(CF / 32, CD / 32, CE), tb, 0, stream>>>(w1, w1t, nullptr, CD, CF);
  k_transpose_split<<<dim3(CD / 32, CF / 32, CE), tb, 0, stream>>>(w2, w2t, nullptr, CF, CD);

  // --- attention ---
  g_qkv<<<dim3(CN / 64, CD / 128, 3), 256, 0, stream>>>(
      srcH, srcL, qwH, qwL, kwH, kwL, vwH, vwL, qH, qL, kH, kL, vTH, vTL);
  k_fattn<<<dim3(CS / 64, CBH), 256, 0, stream>>>(
      qH, qL, kH, kL, vTH, vTL, scale_w, aoH, aoL);
  g_gate<<<dim3(CN / 64, CD / 128, 2), 256, 0, stream>>>(aoH, aoL, gwH, gwL, pbuf);
  k_gatemul<<<dim3(CN * CD / 4 / 256), 256, 0, stream>>>(pbuf, aoH, aoL, gate_b, gdH, gdL);
  g_outp<<<dim3(CN / 64, CD / 128, 2), 256, 0, stream>>>(gdH, gdL, owH, owL, pbuf);
  k_ln1<<<dim3(CN), 256, 0, stream>>>(pbuf, src, n1_g, n1_b, x, xH);

  // --- routing + MoE ---
  k_zero_counts<<<dim3(1), 64, 0, stream>>>(counts);
  k_route<<<dim3(CN / 4), 256, 0, stream>>>(x, moe_gate_w, moe_gate_b, chosen, counts, bucket);
  k_plan<<<dim3(1), 64, 0, stream>>>(counts, tiles);
  g_moe1<<<dim3(40, CF / 128, 2), 256, 0, stream>>>(xH, w1t, counts, bucket, tiles, pbuf);
  k_lngelu<<<dim3(CN), 256, 0, stream>>>(pbuf, chosen, b1, ln_g, ln_b, h2);
  g_moe2<<<dim3(40, CD / 128, 4), 256, 0, stream>>>(h2, w2t, counts, bucket, tiles, pbuf);
  k_ln2<<<dim3(pbuf == nullptr ? CN : CN), 256, 0, stream>>>(pbuf, x, b2, res_scale, chosen, n2_g, n2_b, outp);
}

// Round 6
// 555.174 us; speedup vs baseline: 1.4386x; 1.1141x over previous
//
#include <hip/hip_runtime.h>

// MemoAI fused block for MI355X (gfx950).
//  - fp16x2 split-precision MFMA (hi + 2^11-scaled lo) upstream of MoE routing
//  - plain fp16 MFMA for the expert FFN (post-routing)
//  - sum(softmax(top2)) == 1 -> moe weight multiplier is exactly 1
//  - only the chosen expert is computed (tokens bucketed by expert)
//  - R1: 64x128 LDS-staged GEMM core (global_load_lds width=16)
//  - R2: flash attention (online softmax, register scores), qscale fused
//  - R3: split-K on gate/outp/moe1/moe2 (partials folded into consumers)
//  - R4: MoE GEMMs: tile-compacted grid (k_plan) + single-barrier dbuf K-loop
//  - R5: fattn K/V staged block-cooperatively into LDS (dbuf, single barrier,
//    source-side XOR swizzle) -- was global-load-latency bound (630 GB/s,
//    MfmaUtil 8%); prefetch of chunk k+1 now overlaps chunk k's compute.

typedef _Float16 f16;
typedef _Float16 f16x8 __attribute__((ext_vector_type(8)));
typedef _Float16 f16x4 __attribute__((ext_vector_type(4)));
typedef float f32x4 __attribute__((ext_vector_type(4)));

constexpr int CS  = 1024;  // seq len
constexpr int CD  = 1024;  // model dim
constexpr int CH  = 16;    // heads
constexpr int CHD = 64;    // head dim
constexpr int CF  = 2048;  // ffn dim
constexpr int CE  = 8;     // experts
constexpr int CN  = 2048;  // tokens = B*S
constexpr int CBH = 32;    // B*H
constexpr int KS  = 512;   // split-K slice width
constexpr int MAXT = 48;   // padded tile-table size (true max 39)

constexpr float LO_SCALE = 2048.f;       // 2^11: keeps lo-parts normal in fp16
constexpr float LO_INV   = 1.f / 2048.f;

#define MFMA16(a, b, c) __builtin_amdgcn_mfma_f32_16x16x32_f16((a), (b), (c), 0, 0, 0)

#define TO_GBL(p) ((const __attribute__((address_space(1))) void*)(p))
#define TO_LDS(p) ((__attribute__((address_space(3))) void*)(p))
#define GLD16(g, l) __builtin_amdgcn_global_load_lds(TO_GBL(g), TO_LDS(l), 16, 0, 0)

__device__ __forceinline__ void fsplit(float v, f16 &hi, f16 &lo) {
  hi = (f16)v;
  lo = (f16)((v - (float)hi) * LO_SCALE);
}

// ---------------------------------------------------------------- conversions

__global__ void k_split_cvt(const float* __restrict__ in, f16* __restrict__ oh,
                            f16* __restrict__ ol, int n) {
  int i = (blockIdx.x * blockDim.x + threadIdx.x) * 4;
  if (i >= n) return;
  float4 v = *(const float4*)(in + i);
  float a[4] = {v.x, v.y, v.z, v.w};
#pragma unroll
  for (int j = 0; j < 4; ++j) {
    f16 hi = (f16)a[j];
    oh[i + j] = hi;
    ol[i + j] = (f16)((a[j] - (float)hi) * LO_SCALE);
  }
}

// in: [Z][R][C] f32 -> outH(/outL scaled) : [Z][C][R] f16
__global__ void k_transpose_split(const float* __restrict__ in, f16* __restrict__ oh,
                                  f16* __restrict__ ol, int R, int C) {
  __shared__ float t[32][33];
  const int z = blockIdx.z;
  const float* src = in + (size_t)z * R * C;
  f16* dh = oh + (size_t)z * R * C;
  f16* dl = ol ? ol + (size_t)z * R * C : nullptr;
  const int c0 = blockIdx.x * 32, r0 = blockIdx.y * 32;
  const int tx = threadIdx.x, ty = threadIdx.y;
#pragma unroll
  for (int i = 0; i < 32; i += 8)
    t[ty + i][tx] = src[(size_t)(r0 + ty + i) * C + c0 + tx];
  __syncthreads();
#pragma unroll
  for (int i = 0; i < 32; i += 8) {
    float v = t[tx][ty + i];
    f16 hi = (f16)v;
    size_t idx = (size_t)(c0 + ty + i) * R + r0 + tx;
    dh[idx] = hi;
    if (dl) dl[idx] = (f16)((v - (float)hi) * LO_SCALE);
  }
}

// ------------------------------------------------------------- tiled GEMM core
// Block tile 64(M) x 128(N), BK=32, 4 waves (2x2), wave tile 32x64.

template <bool SPLIT>
__device__ __forceinline__ void gemm_tile(
    const f16* aH, const f16* aL, const f16* bH, const f16* bL,
    size_t bRowStride /* 64*ldb */, int K, f16* lds,
    f32x4 (&accm)[2][4], f32x4 (&accc)[2][4]) {
  f16* lAh = lds;                          // 64*32  = 2048 halves
  f16* lAl = lds + 2048;                   // (split only)
  f16* lBh = lds + (SPLIT ? 4096 : 2048);  // 128*32 = 4096 halves
  f16* lBl = lds + 8192;                   // (split only)
  const int t = threadIdx.x;
  const int lane = t & 63, wave = t >> 6;
  const int wm = wave >> 1, wn = wave & 1;
  const int m16 = lane & 15, quad = lane >> 4;
  int aoff[2], boff[4];
#pragma unroll
  for (int sm = 0; sm < 2; ++sm) {
    const int r = wm * 32 + sm * 16 + m16;
    aoff[sm] = r * 32 + ((quad ^ ((r >> 1) & 3)) * 8);
  }
#pragma unroll
  for (int sn = 0; sn < 4; ++sn) {
    const int r = wn * 64 + sn * 16 + m16;
    boff[sn] = r * 32 + ((quad ^ ((r >> 1) & 3)) * 8);
  }
  for (int k = 0; k < K; k += 32) {
    GLD16(aH, lAh + t * 8);
    GLD16(bH, lBh + t * 8);
    GLD16(bH + bRowStride, lBh + 2048 + t * 8);
    if constexpr (SPLIT) {
      GLD16(aL, lAl + t * 8);
      GLD16(bL, lBl + t * 8);
      GLD16(bL + bRowStride, lBl + 2048 + t * 8);
      aL += 32; bL += 32;
    }
    aH += 32; bH += 32;
    __syncthreads();  // drains vmcnt(0) -> staged data visible
    f16x8 af[2], alf[2], bf[4], blf[4];
#pragma unroll
    for (int sm = 0; sm < 2; ++sm) {
      af[sm] = *(const f16x8*)(lAh + aoff[sm]);
      if constexpr (SPLIT) alf[sm] = *(const f16x8*)(lAl + aoff[sm]);
    }
#pragma unroll
    for (int sn = 0; sn < 4; ++sn) {
      bf[sn] = *(const f16x8*)(lBh + boff[sn]);
      if constexpr (SPLIT) blf[sn] = *(const f16x8*)(lBl + boff[sn]);
    }
#pragma unroll
    for (int sm = 0; sm < 2; ++sm)
#pragma unroll
      for (int sn = 0; sn < 4; ++sn) {
        accm[sm][sn] = MFMA16(af[sm], bf[sn], accm[sm][sn]);
        if constexpr (SPLIT) {
          accc[sm][sn] = MFMA16(af[sm], blf[sn], accc[sm][sn]);
          accc[sm][sn] = MFMA16(alf[sm], bf[sn], accc[sm][sn]);
        }
      }
    __syncthreads();  // all waves done reading before next overwrite
  }
}

// Double-buffered single-barrier variant (non-split). LDS = 2 x 6144 halves.
__device__ __forceinline__ void gemm_tile_db(
    const f16* aH, const f16* bH, size_t bRowStride, int K, f16* lds,
    f32x4 (&accm)[2][4]) {
  const int t = threadIdx.x;
  const int lane = t & 63, wave = t >> 6;
  const int wm = wave >> 1, wn = wave & 1;
  const int m16 = lane & 15, quad = lane >> 4;
  int aoff[2], boff[4];
#pragma unroll
  for (int sm = 0; sm < 2; ++sm) {
    const int r = wm * 32 + sm * 16 + m16;
    aoff[sm] = r * 32 + ((quad ^ ((r >> 1) & 3)) * 8);
  }
#pragma unroll
  for (int sn = 0; sn < 4; ++sn) {
    const int r = wn * 64 + sn * 16 + m16;
    boff[sn] = 2048 + r * 32 + ((quad ^ ((r >> 1) & 3)) * 8);
  }
  GLD16(aH, lds + t * 8);
  GLD16(bH, lds + 2048 + t * 8);
  GLD16(bH + bRowStride, lds + 4096 + t * 8);
  aH += 32; bH += 32;
  int cur = 0;
  for (int k = 0; k < K; k += 32) {
    __syncthreads();  // buf[cur] staged (vmcnt0) + prev buffer fully consumed
    f16* buf = lds + cur * 6144;
    f16* nbuf = lds + (cur ^ 1) * 6144;
    if (k + 32 < K) {
      GLD16(aH, nbuf + t * 8);
      GLD16(bH, nbuf + 2048 + t * 8);
      GLD16(bH + bRowStride, nbuf + 4096 + t * 8);
      aH += 32; bH += 32;
    }
    f16x8 af[2], bf[4];
#pragma unroll
    for (int sm = 0; sm < 2; ++sm) af[sm] = *(const f16x8*)(buf + aoff[sm]);
#pragma unroll
    for (int sn = 0; sn < 4; ++sn) bf[sn] = *(const f16x8*)(buf + boff[sn]);
#pragma unroll
    for (int sm = 0; sm < 2; ++sm)
#pragma unroll
      for (int sn = 0; sn < 4; ++sn)
        accm[sm][sn] = MFMA16(af[sm], bf[sn], accm[sm][sn]);
    cur ^= 1;
  }
}

// ---------------------------------------------------------------- QKV

__global__ __launch_bounds__(256) void g_qkv(
    const f16* __restrict__ srcH, const f16* __restrict__ srcL,
    const f16* __restrict__ qwH, const f16* __restrict__ qwL,
    const f16* __restrict__ kwH, const f16* __restrict__ kwL,
    const f16* __restrict__ vwH, const f16* __restrict__ vwL,
    f16* __restrict__ qHo, f16* __restrict__ qLo,
    f16* __restrict__ kHo, f16* __restrict__ kLo,
    f16* __restrict__ vTH, f16* __restrict__ vTL) {
  __shared__ f16 lds[12288];
  const int z = blockIdx.z;
  const int m0 = blockIdx.x * 64, n0 = blockIdx.y * 128;
  const int t = threadIdx.x;
  const int rowS = t >> 2;
  const int ksw = ((t & 3) ^ ((rowS >> 1) & 3)) * 8;
  const f16* BH = (z == 0) ? qwH : (z == 1) ? kwH : vwH;
  const f16* BL = (z == 0) ? qwL : (z == 1) ? kwL : vwL;
  const f32x4 VZ = {0.f, 0.f, 0.f, 0.f};
  f32x4 accm[2][4], accc[2][4];
#pragma unroll
  for (int i = 0; i < 2; ++i)
#pragma unroll
    for (int j = 0; j < 4; ++j) { accm[i][j] = VZ; accc[i][j] = VZ; }
  gemm_tile<true>(srcH + (size_t)(m0 + rowS) * CD + ksw,
                  srcL + (size_t)(m0 + rowS) * CD + ksw,
                  BH + (size_t)(n0 + rowS) * CD + ksw,
                  BL + (size_t)(n0 + rowS) * CD + ksw,
                  (size_t)64 * CD, CD, lds, accm, accc);
  const int lane = t & 63, wave = t >> 6;
  const int wm = wave >> 1, wn = wave & 1;
  const int m16 = lane & 15, quad = lane >> 4;
#pragma unroll
  for (int sm = 0; sm < 2; ++sm)
#pragma unroll
    for (int sn = 0; sn < 4; ++sn)
#pragma unroll
      for (int r = 0; r < 4; ++r) {
        const int row = m0 + wm * 32 + sm * 16 + quad * 4 + r;  // token
        const int col = n0 + wn * 64 + sn * 16 + m16;           // d
        const float v = accm[sm][sn][r] + accc[sm][sn][r] * LO_INV;
        f16 hi, lo; fsplit(v, hi, lo);
        const int bb = row >> 10, ss = row & 1023;
        const int hh = col >> 6, hd = col & 63;
        if (z == 2) {  // v stored transposed: [b,h,hd,s]
          const size_t idx = ((size_t)((bb * CH + hh) * CHD + hd)) * CS + ss;
          vTH[idx] = hi; vTL[idx] = lo;
        } else {
          const size_t idx = ((size_t)((bb * CH + hh) * CS + ss)) * CHD + hd;
          if (z == 0) { qHo[idx] = hi; qLo[idx] = lo; }
          else        { kHo[idx] = hi; kLo[idx] = lo; }
        }
      }
}

// ------------------------------------------------------- flash attention
// R5: K/V chunk (64 keys: K hi/lo row-major [key][hd], V hi/lo [hd][key])
// staged into LDS once per block via global_load_lds, double-buffered with a
// single barrier per chunk. 128B rows are stored with the 16B-granule chunk
// position XORed by (row&7) on the SOURCE side, so fragment ds_read_b128
// (lane = row) is 2-way bank-aliased (free).

__device__ __forceinline__ int pswz(int q, int k) {
  return q * 64 + ((((k >> 2) ^ q) & 15) << 2) + (k & 3);
}

__global__ __launch_bounds__(256) void k_fattn(
    const f16* __restrict__ qH_, const f16* __restrict__ qL_,
    const f16* __restrict__ kH_, const f16* __restrict__ kL_,
    const f16* __restrict__ vTH_, const f16* __restrict__ vTL_,
    const float* __restrict__ scale_w,
    f16* __restrict__ aoH, f16* __restrict__ aoL) {
  __shared__ f16 kvb[32768];       // 2 x (Khi|Klo|Vhi|Vlo, 4096 halves each)
  __shared__ float psc[4 * 1024];  // 4 waves x (16x64) P tile, swizzled
  const int bh = blockIdx.y;
  const int b = bh >> 4, h = bh & 15;
  const int t = threadIdx.x;
  const int lane = t & 63, wave = t >> 6;
  const int m16 = lane & 15, quad = lane >> 4;
  const int q0 = blockIdx.x * 64 + wave * 16;  // this wave's q rows
  float* P = psc + wave * 1024;
  const f32x4 VZ = {0.f, 0.f, 0.f, 0.f};
  const size_t kb = (size_t)bh * CS * CHD;  // == bh * CHD * CS

  // stage one 64-key chunk (32 KB) into dst
  const int rowS = t >> 3, chS = t & 7;
  auto stage = [&](f16* dst, int kc) {
#pragma unroll
    for (int i = 0; i < 2; ++i) {
      const int row = rowS + 32 * i;
      const int sc = (chS ^ (row & 7)) * 8;
      GLD16(kH_ + kb + (size_t)(kc + row) * CHD + sc, dst + i * 2048 + t * 8);
      GLD16(kL_ + kb + (size_t)(kc + row) * CHD + sc, dst + 4096 + i * 2048 + t * 8);
      GLD16(vTH_ + kb + (size_t)row * CS + kc + sc, dst + 8192 + i * 2048 + t * 8);
      GLD16(vTL_ + kb + (size_t)row * CS + kc + sc, dst + 12288 + i * 2048 + t * 8);
    }
  };
  // fragment read: logical 16B chunk q (0..7) of row r within a 4096-half piece
  auto ldf = [&](const f16* piece, int r, int q) -> f16x8 {
    return *(const f16x8*)(piece + r * 64 + ((q ^ (r & 7)) * 8));
  };

  // Q fragments (A-layout), hi+lo
  const f16* qrh = qH_ + ((size_t)bh * CS + q0 + m16) * CHD + quad * 8;
  const f16* qrl = qL_ + ((size_t)bh * CS + q0 + m16) * CHD + quad * 8;
  f16x8 a0h = *(const f16x8*)(qrh);
  f16x8 a1h = *(const f16x8*)(qrh + 32);
  f16x8 a0l = *(const f16x8*)(qrl);
  f16x8 a1l = *(const f16x8*)(qrl + 32);

  stage(kvb, 0);  // prologue: chunk 0 -> buf 0

  // fused dynamic scale: row factor = 2*sigmoid(q . scale_w[h]) / sqrt(64)
  float dot = 0.f;
  {
    const float* sw = scale_w + h * CHD + quad * 8;
    float4 s0 = *(const float4*)(sw);
    float4 s1 = *(const float4*)(sw + 4);
    float4 s2 = *(const float4*)(sw + 32);
    float4 s3 = *(const float4*)(sw + 36);
    float sv[16] = {s0.x, s0.y, s0.z, s0.w, s1.x, s1.y, s1.z, s1.w,
                    s2.x, s2.y, s2.z, s2.w, s3.x, s3.y, s3.z, s3.w};
#pragma unroll
    for (int j = 0; j < 8; ++j) {
      dot += ((float)a0h[j] + (float)a0l[j] * LO_INV) * sv[j];
      dot += ((float)a1h[j] + (float)a1l[j] * LO_INV) * sv[8 + j];
    }
    dot += __shfl_xor(dot, 16);
    dot += __shfl_xor(dot, 32);
  }
  const float qsv = 2.f / (1.f + __expf(-dot));  // for row q0+m16
  float qsr[4];
#pragma unroll
  for (int r = 0; r < 4; ++r) qsr[r] = __shfl(qsv, quad * 4 + r) * 0.125f;

  f32x4 accm[4], accc[4];  // out accumulator: 4 hd-tiles, C-layout
#pragma unroll
  for (int tt = 0; tt < 4; ++tt) { accm[tt] = VZ; accc[tt] = VZ; }
  float mrun[4], lrun[4];
#pragma unroll
  for (int r = 0; r < 4; ++r) { mrun[r] = -1e30f; lrun[r] = 0.f; }

  int cur = 0;
  for (int kc = 0; kc < CS; kc += 64) {
    __syncthreads();  // buf[cur] staged (vmcnt drained) + prev buf consumed
    const f16* kv = kvb + cur * 16384;
    if (kc + 64 < CS) stage(kvb + (cur ^ 1) * 16384, kc + 64);

    // --- S = (Q K^T) * qs, 4 key tiles (fp32-exact via split)
    f32x4 st[4];
#pragma unroll
    for (int tt = 0; tt < 4; ++tt) {
      const int r = tt * 16 + m16;
      f16x8 b0h = ldf(kv,        r, quad);
      f16x8 b1h = ldf(kv,        r, quad + 4);
      f16x8 b0l = ldf(kv + 4096, r, quad);
      f16x8 b1l = ldf(kv + 4096, r, quad + 4);
      f32x4 am = VZ, ac = VZ;
      am = MFMA16(a0h, b0h, am); am = MFMA16(a1h, b1h, am);
      ac = MFMA16(a0h, b0l, ac); ac = MFMA16(a0l, b0h, ac);
      ac = MFMA16(a1h, b1l, ac); ac = MFMA16(a1l, b1h, ac);
#pragma unroll
      for (int r4 = 0; r4 < 4; ++r4)
        st[tt][r4] = (am[r4] + ac[r4] * LO_INV) * qsr[r4];
    }
    // --- online max update
    float alpha[4];
#pragma unroll
    for (int r = 0; r < 4; ++r) {
      float mx = fmaxf(fmaxf(st[0][r], st[1][r]), fmaxf(st[2][r], st[3][r]));
#pragma unroll
      for (int msk = 8; msk >= 1; msk >>= 1) mx = fmaxf(mx, __shfl_xor(mx, msk));
      const float mnew = fmaxf(mrun[r], mx);
      alpha[r] = __expf(mrun[r] - mnew);
      mrun[r] = mnew;
    }
    // --- exp, row-sum, stash P (C-layout) into wave-private swizzled LDS
    float rs[4] = {0.f, 0.f, 0.f, 0.f};
#pragma unroll
    for (int tt = 0; tt < 4; ++tt)
#pragma unroll
      for (int r = 0; r < 4; ++r) {
        const float e = __expf(st[tt][r] - mrun[r]);
        rs[r] += e;
        P[pswz(quad * 4 + r, tt * 16 + m16)] = e;
      }
#pragma unroll
    for (int r = 0; r < 4; ++r) {
#pragma unroll
      for (int msk = 8; msk >= 1; msk >>= 1) rs[r] += __shfl_xor(rs[r], msk);
      lrun[r] = lrun[r] * alpha[r] + rs[r];
#pragma unroll
      for (int tt = 0; tt < 4; ++tt) { accm[tt][r] *= alpha[r]; accc[tt][r] *= alpha[r]; }
    }
    // --- read P back in A-layout, split hi/lo
    f16x8 pah[2], pal[2];
#pragma unroll
    for (int c = 0; c < 2; ++c) {
      const int k0 = c * 32 + quad * 8;
      float4 p0 = *(const float4*)(P + pswz(m16, k0));
      float4 p1 = *(const float4*)(P + pswz(m16, k0 + 4));
      float pv[8] = {p0.x, p0.y, p0.z, p0.w, p1.x, p1.y, p1.z, p1.w};
#pragma unroll
      for (int j = 0; j < 8; ++j) {
        f16 hi = (f16)pv[j];
        pah[c][j] = hi;
        pal[c][j] = (f16)((pv[j] - (float)hi) * LO_SCALE);
      }
    }
    // --- O += P V  (V^T fragments from LDS)
#pragma unroll
    for (int tt = 0; tt < 4; ++tt) {
      const int r = tt * 16 + m16;  // hd row
#pragma unroll
      for (int c = 0; c < 2; ++c) {
        f16x8 vbh = ldf(kv + 8192,  r, quad + 4 * c);
        f16x8 vbl = ldf(kv + 12288, r, quad + 4 * c);
        accm[tt] = MFMA16(pah[c], vbh, accm[tt]);
        accc[tt] = MFMA16(pah[c], vbl, accc[tt]);
        accc[tt] = MFMA16(pal[c], vbh, accc[tt]);
      }
    }
    cur ^= 1;
  }
  // --- epilogue: normalize by l, split-store
#pragma unroll
  for (int tt = 0; tt < 4; ++tt)
#pragma unroll
    for (int r = 0; r < 4; ++r) {
      const int row = q0 + quad * 4 + r;
      const float v = (accm[tt][r] + accc[tt][r] * LO_INV) / lrun[r];
      f16 hi, lo; fsplit(v, hi, lo);
      const size_t idx = ((size_t)(b * CS + row)) * CD + h * CHD + tt * 16 + m16;
      aoH[idx] = hi; aoL[idx] = lo;
    }
}

// ------------------------------------------- gate / out (split-K partials)

__global__ __launch_bounds__(256) void g_gate(
    const f16* __restrict__ aoH, const f16* __restrict__ aoL,
    const f16* __restrict__ gwH, const f16* __restrict__ gwL,
    float* __restrict__ gpre /* [2][CN*CD] */) {
  __shared__ f16 lds[12288];
  const int m0 = blockIdx.x * 64, n0 = blockIdx.y * 128, s = blockIdx.z;
  const int t = threadIdx.x;
  const int rowS = t >> 2;
  const int ksw = ((t & 3) ^ ((rowS >> 1) & 3)) * 8;
  const int k0 = s * KS;
  const f32x4 VZ = {0.f, 0.f, 0.f, 0.f};
  f32x4 accm[2][4], accc[2][4];
#pragma unroll
  for (int i = 0; i < 2; ++i)
#pragma unroll
    for (int j = 0; j < 4; ++j) { accm[i][j] = VZ; accc[i][j] = VZ; }
  gemm_tile<true>(aoH + (size_t)(m0 + rowS) * CD + k0 + ksw,
                  aoL + (size_t)(m0 + rowS) * CD + k0 + ksw,
                  gwH + (size_t)(n0 + rowS) * CD + k0 + ksw,
                  gwL + (size_t)(n0 + rowS) * CD + k0 + ksw,
                  (size_t)64 * CD, KS, lds, accm, accc);
  float* gp = gpre + (size_t)s * CN * CD;
  const int lane = t & 63, wave = t >> 6;
  const int wm = wave >> 1, wn = wave & 1;
  const int m16 = lane & 15, quad = lane >> 4;
#pragma unroll
  for (int sm = 0; sm < 2; ++sm)
#pragma unroll
    for (int sn = 0; sn < 4; ++sn)
#pragma unroll
      for (int r = 0; r < 4; ++r) {
        const int row = m0 + wm * 32 + sm * 16 + quad * 4 + r;
        const int col = n0 + wn * 64 + sn * 16 + m16;
        gp[(size_t)row * CD + col] = accm[sm][sn][r] + accc[sm][sn][r] * LO_INV;
      }
}

// gd = fsplit(ao * sigmoid(gpre0+gpre1+gate_b))
__global__ __launch_bounds__(256) void k_gatemul(
    const float* __restrict__ gpre, const f16* __restrict__ aoH,
    const f16* __restrict__ aoL, const float* __restrict__ gate_b,
    f16* __restrict__ gdH, f16* __restrict__ gdL) {
  const int i = (blockIdx.x * 256 + threadIdx.x) * 4;
  float4 p0 = *(const float4*)(gpre + i);
  float4 p1 = *(const float4*)(gpre + (size_t)CN * CD + i);
  float4 gb = *(const float4*)(gate_b + (i & (CD - 1)));
  f16x4 ah = *(const f16x4*)(aoH + i);
  f16x4 al = *(const f16x4*)(aoL + i);
  float pre[4] = {p0.x + p1.x + gb.x, p0.y + p1.y + gb.y,
                  p0.z + p1.z + gb.z, p0.w + p1.w + gb.w};
  f16x4 oh, ol;
#pragma unroll
  for (int j = 0; j < 4; ++j) {
    const float g = 1.f / (1.f + __expf(-pre[j]));
    const float ov = ((float)ah[j] + (float)al[j] * LO_INV) * g;
    f16 hi, lo; fsplit(ov, hi, lo);
    oh[j] = hi; ol[j] = lo;
  }
  *(f16x4*)(gdH + i) = oh;
  *(f16x4*)(gdL + i) = ol;
}

__global__ __launch_bounds__(256) void g_outp(
    const f16* __restrict__ gdH, const f16* __restrict__ gdL,
    const f16* __restrict__ owH, const f16* __restrict__ owL,
    float* __restrict__ y1p /* [2][CN*CD] */) {
  __shared__ f16 lds[12288];
  const int m0 = blockIdx.x * 64, n0 = blockIdx.y * 128, s = blockIdx.z;
  const int t = threadIdx.x;
  const int rowS = t >> 2;
  const int ksw = ((t & 3) ^ ((rowS >> 1) & 3)) * 8;
  const int k0 = s * KS;
  const f32x4 VZ = {0.f, 0.f, 0.f, 0.f};
  f32x4 accm[2][4], accc[2][4];
#pragma unroll
  for (int i = 0; i < 2; ++i)
#pragma unroll
    for (int j = 0; j < 4; ++j) { accm[i][j] = VZ; accc[i][j] = VZ; }
  gemm_tile<true>(gdH + (size_t)(m0 + rowS) * CD + k0 + ksw,
                  gdL + (size_t)(m0 + rowS) * CD + k0 + ksw,
                  owH + (size_t)(n0 + rowS) * CD + k0 + ksw,
                  owL + (size_t)(n0 + rowS) * CD + k0 + ksw,
                  (size_t)64 * CD, KS, lds, accm, accc);
  float* yp = y1p + (size_t)s * CN * CD;
  const int lane = t & 63, wave = t >> 6;
  const int wm = wave >> 1, wn = wave & 1;
  const int m16 = lane & 15, quad = lane >> 4;
#pragma unroll
  for (int sm = 0; sm < 2; ++sm)
#pragma unroll
    for (int sn = 0; sn < 4; ++sn)
#pragma unroll
      for (int r = 0; r < 4; ++r) {
        const int row = m0 + wm * 32 + sm * 16 + quad * 4 + r;
        const int col = n0 + wn * 64 + sn * 16 + m16;
        yp[(size_t)row * CD + col] = accm[sm][sn][r] + accc[sm][sn][r] * LO_INV;
      }
}

// -------------------------------------------------------------- layernorms

__device__ __forceinline__ void block_reduce2(float &s, float &ss, float* red) {
#pragma unroll
  for (int msk = 32; msk >= 1; msk >>= 1) {
    s += __shfl_xor(s, msk);
    ss += __shfl_xor(ss, msk);
  }
  const int wave = threadIdx.x >> 6, lane = threadIdx.x & 63;
  if (lane == 0) { red[wave] = s; red[4 + wave] = ss; }
  __syncthreads();
  s = red[0] + red[1] + red[2] + red[3];
  ss = red[4] + red[5] + red[6] + red[7];
}

// x = LN(src + y1p0 + y1p1)
__global__ __launch_bounds__(256) void k_ln1(
    const float* __restrict__ y1p, const float* __restrict__ srcp,
    const float* __restrict__ g, const float* __restrict__ bb,
    float* __restrict__ x, f16* __restrict__ xH) {
  __shared__ float red[8];
  const int n = blockIdx.x;
  const int t = threadIdx.x;
  const size_t off = (size_t)n * CD + t * 4;
  float4 v0 = *(const float4*)(y1p + off);
  float4 v1 = *(const float4*)(y1p + (size_t)CN * CD + off);
  float4 v2 = *(const float4*)(srcp + off);
  float a[4] = {v0.x + v1.x + v2.x, v0.y + v1.y + v2.y,
                v0.z + v1.z + v2.z, v0.w + v1.w + v2.w};
  float s = a[0] + a[1] + a[2] + a[3];
  float ss = a[0]*a[0] + a[1]*a[1] + a[2]*a[2] + a[3]*a[3];
  block_reduce2(s, ss, red);
  const float mean = s * (1.f / CD);
  const float var = ss * (1.f / CD) - mean * mean;
  const float rstd = rsqrtf(var + 1e-5f);
#pragma unroll
  for (int j = 0; j < 4; ++j) {
    const int d = t * 4 + j;
    const float val = (a[j] - mean) * rstd * g[d] + bb[d];
    x[(size_t)n * CD + d] = val;
    xH[(size_t)n * CD + d] = (f16)val;
  }
}

// out = LN2( 2*x + (zbp0+..+zbp3 + b2[e])*rs[e] )
__global__ __launch_bounds__(256) void k_ln2(
    const float* __restrict__ zbp, const float* __restrict__ x,
    const float* __restrict__ b2, const float* __restrict__ rsc,
    const int* __restrict__ chosen,
    const float* __restrict__ g, const float* __restrict__ bb,
    float* __restrict__ outp) {
  __shared__ float red[8];
  const int n = blockIdx.x;
  const int e = chosen[n];
  const float rs = rsc[e];
  const int t = threadIdx.x;
  const size_t off = (size_t)n * CD + t * 4;
  float4 p0 = *(const float4*)(zbp + off);
  float4 p1 = *(const float4*)(zbp + (size_t)CN * CD + off);
  float4 p2 = *(const float4*)(zbp + (size_t)2 * CN * CD + off);
  float4 p3 = *(const float4*)(zbp + (size_t)3 * CN * CD + off);
  float4 xv = *(const float4*)(x + off);
  float4 bv = *(const float4*)(b2 + (size_t)e * CD + t * 4);
  float a[4] = {2.f * xv.x + (p0.x + p1.x + p2.x + p3.x + bv.x) * rs,
                2.f * xv.y + (p0.y + p1.y + p2.y + p3.y + bv.y) * rs,
                2.f * xv.z + (p0.z + p1.z + p2.z + p3.z + bv.z) * rs,
                2.f * xv.w + (p0.w + p1.w + p2.w + p3.w + bv.w) * rs};
  float s = a[0] + a[1] + a[2] + a[3];
  float ss = a[0]*a[0] + a[1]*a[1] + a[2]*a[2] + a[3]*a[3];
  block_reduce2(s, ss, red);
  const float mean = s * (1.f / CD);
  const float var = ss * (1.f / CD) - mean * mean;
  const float rstd = rsqrtf(var + 1e-5f);
#pragma unroll
  for (int j = 0; j < 4; ++j) {
    const int d = t * 4 + j;
    outp[(size_t)n * CD + d] = (a[j] - mean) * rstd * g[d] + bb[d];
  }
}

// ------------------------------------------------------------------ routing

__global__ void k_zero_counts(int* counts) {
  if (threadIdx.x < CE) counts[threadIdx.x] = 0;
}

__global__ __launch_bounds__(256) void k_route(
    const float* __restrict__ x, const float* __restrict__ gw, const float* __restrict__ gb,
    int* __restrict__ chosen, int* __restrict__ counts, int* __restrict__ bucket) {
  const int wave = threadIdx.x >> 6, lane = threadIdx.x & 63;
  const int n = blockIdx.x * 4 + wave;
  const float* xr = x + (size_t)n * CD;
  float acc[CE];
#pragma unroll
  for (int e = 0; e < CE; ++e) acc[e] = 0.f;
  for (int j = 0; j < 16; ++j) {
    const int d = lane * 16 + j;
    const float xv = xr[d];
    const float* wr = gw + (size_t)d * CE;
#pragma unroll
    for (int e = 0; e < CE; ++e) acc[e] += xv * wr[e];
  }
#pragma unroll
  for (int msk = 32; msk >= 1; msk >>= 1) {
#pragma unroll
    for (int e = 0; e < CE; ++e) acc[e] += __shfl_xor(acc[e], msk);
  }
  if (lane == 0) {
    float best = -1e30f, second = -1e30f;
    int bi = 0, si = 0;
#pragma unroll
    for (int e = 0; e < CE; ++e) {
      const float L = acc[e] + gb[e];
      if (L > best) { second = best; si = bi; best = L; bi = e; }
      else if (L > second) { second = L; si = e; }
    }
    const int ch = bi > si ? bi : si;  // torch-loop semantics: max index wins
    chosen[n] = ch;
    const int pos = atomicAdd(&counts[ch], 1);
    bucket[ch * CN + pos] = n;
  }
}

// build dense tile table: (expert, m0) for every 64-row tile of every expert
__global__ void k_plan(const int* __restrict__ counts, int* __restrict__ tiles) {
  if (threadIdx.x == 0) {
    int n = 0;
    for (int e = 0; e < CE; ++e) {
      const int c = counts[e];
      for (int m0 = 0; m0 < c; m0 += 64) { tiles[2 * n] = e; tiles[2 * n + 1] = m0; ++n; }
    }
    for (; n < MAXT; ++n) { tiles[2 * n] = -1; tiles[2 * n + 1] = 0; }
  }
}

// ------------------------------------------------------------------ MoE FFN

__global__ __launch_bounds__(256) void g_moe1(
    const f16* __restrict__ xH, const f16* __restrict__ w1t,
    const int* __restrict__ counts, const int* __restrict__ bucket,
    const int* __restrict__ tiles, float* __restrict__ hbp /* [2][CN*CF] */) {
  const int e = tiles[2 * blockIdx.x];
  if (e < 0) return;
  const int m0 = tiles[2 * blockIdx.x + 1];
  const int cnt = counts[e];
  const int s = blockIdx.z;
  __shared__ f16 lds[12288];  // 2 x 6144 (dbuf)
  const int t = threadIdx.x;
  const int rowS = t >> 2;
  const int ksw = ((t & 3) ^ ((rowS >> 1) & 3)) * 8;
  const int k0 = s * KS;
  int ra = m0 + rowS; if (ra > cnt - 1) ra = cnt - 1;
  const int tokA = bucket[e * CN + ra];
  const int n0 = blockIdx.y * 128;
  const f32x4 VZ = {0.f, 0.f, 0.f, 0.f};
  f32x4 accm[2][4];
#pragma unroll
  for (int i = 0; i < 2; ++i)
#pragma unroll
    for (int j = 0; j < 4; ++j) accm[i][j] = VZ;
  gemm_tile_db(xH + (size_t)tokA * CD + k0 + ksw,
               w1t + ((size_t)e * CF + n0 + rowS) * CD + k0 + ksw,
               (size_t)64 * CD, KS, lds, accm);
  float* hp = hbp + (size_t)s * CN * CF;
  const int lane = t & 63, wave = t >> 6;
  const int wm = wave >> 1, wn = wave & 1;
  const int m16 = lane & 15, quad = lane >> 4;
#pragma unroll
  for (int sm = 0; sm < 2; ++sm)
#pragma unroll
    for (int sn = 0; sn < 4; ++sn)
#pragma unroll
      for (int r = 0; r < 4; ++r) {
        const int rr = m0 + wm * 32 + sm * 16 + quad * 4 + r;
        if (rr >= cnt) continue;
        const int tok = bucket[e * CN + rr];
        const int col = n0 + wn * 64 + sn * 16 + m16;
        hp[(size_t)tok * CF + col] = accm[sm][sn][r];
      }
}

// h2 = gelu(LN_e(hbp0+hbp1+b1[e]))
__global__ __launch_bounds__(256) void k_lngelu(
    const float* __restrict__ hbp, const int* __restrict__ chosen,
    const float* __restrict__ b1,
    const float* __restrict__ ln_g, const float* __restrict__ ln_b,
    f16* __restrict__ h2) {
  __shared__ float red[8];
  const int n = blockIdx.x;
  const int e = chosen[n];
  const int t = threadIdx.x;
  const size_t off = (size_t)n * CF + t * 8;
  float4 v0 = *(const float4*)(hbp + off);
  float4 v1 = *(const float4*)(hbp + off + 4);
  float4 u0 = *(const float4*)(hbp + (size_t)CN * CF + off);
  float4 u1 = *(const float4*)(hbp + (size_t)CN * CF + off + 4);
  float4 b0 = *(const float4*)(b1 + (size_t)e * CF + t * 8);
  float4 b1v = *(const float4*)(b1 + (size_t)e * CF + t * 8 + 4);
  float a[8] = {v0.x + u0.x + b0.x, v0.y + u0.y + b0.y,
                v0.z + u0.z + b0.z, v0.w + u0.w + b0.w,
                v1.x + u1.x + b1v.x, v1.y + u1.y + b1v.y,
                v1.z + u1.z + b1v.z, v1.w + u1.w + b1v.w};
  float s = 0.f, ss = 0.f;
#pragma unroll
  for (int j = 0; j < 8; ++j) { s += a[j]; ss += a[j] * a[j]; }
  block_reduce2(s, ss, red);
  const float mean = s * (1.f / CF);
  const float var = ss * (1.f / CF) - mean * mean;
  const float rstd = rsqrtf(var + 1e-5f);
  const float* g = ln_g + (size_t)e * CF;
  const float* bb = ln_b + (size_t)e * CF;
#pragma unroll
  for (int j = 0; j < 8; ++j) {
    const int d = t * 8 + j;
    const float val = (a[j] - mean) * rstd * g[d] + bb[d];
    const float gl = 0.5f * val * (1.f + erff(val * 0.70710678118654752f));
    h2[(size_t)n * CF + d] = (f16)gl;
  }
}

__global__ __launch_bounds__(256) void g_moe2(
    const f16* __restrict__ h2, const f16* __restrict__ w2t,
    const int* __restrict__ counts, const int* __restrict__ bucket,
    const int* __restrict__ tiles, float* __restrict__ zbp /* [4][CN*CD] */) {
  const int e = tiles[2 * blockIdx.x];
  if (e < 0) return;
  const int m0 = tiles[2 * blockIdx.x + 1];
  const int cnt = counts[e];
  const int s = blockIdx.z;
  __shared__ f16 lds[12288];  // 2 x 6144 (dbuf)
  const int t = threadIdx.x;
  const int rowS = t >> 2;
  const int ksw = ((t & 3) ^ ((rowS >> 1) & 3)) * 8;
  const int k0 = s * KS;
  int ra = m0 + rowS; if (ra > cnt - 1) ra = cnt - 1;
  const int tokA = bucket[e * CN + ra];
  const int n0 = blockIdx.y * 128;
  const f32x4 VZ = {0.f, 0.f, 0.f, 0.f};
  f32x4 accm[2][4];
#pragma unroll
  for (int i = 0; i < 2; ++i)
#pragma unroll
    for (int j = 0; j < 4; ++j) accm[i][j] = VZ;
  gemm_tile_db(h2 + (size_t)tokA * CF + k0 + ksw,
               w2t + ((size_t)e * CD + n0 + rowS) * CF + k0 + ksw,
               (size_t)64 * CF, KS, lds, accm);
  float* zp = zbp + (size_t)s * CN * CD;
  const int lane = t & 63, wave = t >> 6;
  const int wm = wave >> 1, wn = wave & 1;
  const int m16 = lane & 15, quad = lane >> 4;
#pragma unroll
  for (int sm = 0; sm < 2; ++sm)
#pragma unroll
    for (int sn = 0; sn < 4; ++sn)
#pragma unroll
      for (int r = 0; r < 4; ++r) {
        const int rr = m0 + wm * 32 + sm * 16 + quad * 4 + r;
        if (rr >= cnt) continue;
        const int tok = bucket[e * CN + rr];
        const int col = n0 + wn * 64 + sn * 16 + m16;
        zp[(size_t)tok * CD + col] = accm[sm][sn][r];
      }
}

// ------------------------------------------------------------------- launch

extern "C" void kernel_launch(void* const* d_in, const int* in_sizes, int n_in,
                              void* d_out, int out_size, void* d_ws, size_t ws_size,
                              hipStream_t stream) {
  (void)in_sizes; (void)n_in; (void)out_size; (void)ws_size;
  const float* src        = (const float*)d_in[0];
  const float* q_w        = (const float*)d_in[1];
  const float* k_w        = (const float*)d_in[2];
  const float* v_w        = (const float*)d_in[3];
  const float* out_w      = (const float*)d_in[4];
  const float* gate_w     = (const float*)d_in[5];
  const float* gate_b     = (const float*)d_in[6];
  const float* scale_w    = (const float*)d_in[7];
  const float* n1_g       = (const float*)d_in[8];
  const float* n1_b       = (const float*)d_in[9];
  const float* n2_g       = (const float*)d_in[10];
  const float* n2_b       = (const float*)d_in[11];
  const float* moe_gate_w = (const float*)d_in[12];
  const float* moe_gate_b = (const float*)d_in[13];
  const float* w1         = (const float*)d_in[14];
  const float* b1         = (const float*)d_in[15];
  const float* ln_g       = (const float*)d_in[16];
  const float* ln_b       = (const float*)d_in[17];
  const float* w2         = (const float*)d_in[18];
  const float* b2         = (const float*)d_in[19];
  const float* res_scale  = (const float*)d_in[20];
  float* outp = (float*)d_out;

  char* p = (char*)d_ws;
  auto take = [&](size_t bytes) -> char* {
    char* r = p;
    p += (bytes + 255) & ~(size_t)255;
    return r;
  };
  f16* srcH = (f16*)take((size_t)CN * CD * 2);
  f16* srcL = (f16*)take((size_t)CN * CD * 2);
  f16* qwH = (f16*)take((size_t)CD * CD * 2);
  f16* qwL = (f16*)take((size_t)CD * CD * 2);
  f16* kwH = (f16*)take((size_t)CD * CD * 2);
  f16* kwL = (f16*)take((size_t)CD * CD * 2);
  f16* vwH = (f16*)take((size_t)CD * CD * 2);
  f16* vwL = (f16*)take((size_t)CD * CD * 2);
  f16* gwH = (f16*)take((size_t)CD * CD * 2);
  f16* gwL = (f16*)take((size_t)CD * CD * 2);
  f16* owH = (f16*)take((size_t)CD * CD * 2);
  f16* owL = (f16*)take((size_t)CD * CD * 2);
  f16* qH = (f16*)take((size_t)CBH * CS * CHD * 2);
  f16* qL = (f16*)take((size_t)CBH * CS * CHD * 2);
  f16* kH = (f16*)take((size_t)CBH * CS * CHD * 2);
  f16* kL = (f16*)take((size_t)CBH * CS * CHD * 2);
  f16* vTH = (f16*)take((size_t)CBH * CS * CHD * 2);
  f16* vTL = (f16*)take((size_t)CBH * CS * CHD * 2);
  f16* aoH = (f16*)take((size_t)CN * CD * 2);
  f16* aoL = (f16*)take((size_t)CN * CD * 2);
  f16* gdH = (f16*)take((size_t)CN * CD * 2);
  f16* gdL = (f16*)take((size_t)CN * CD * 2);
  float* x  = (float*)take((size_t)CN * CD * 4);
  f16* xH = (f16*)take((size_t)CN * CD * 2);
  int* counts = (int*)take(64);
  int* bucket = (int*)take((size_t)CE * CN * 4);
  int* chosen = (int*)take((size_t)CN * 4);
  int* tiles = (int*)take((size_t)MAXT * 2 * 4);
  f16* h2 = (f16*)take((size_t)CN * CF * 2);
  f16* w1t = (f16*)take((size_t)CE * CF * CD * 2);
  f16* w2t = (f16*)take((size_t)CE * CD * CF * 2);
  // time-shared 32 MB fp32 partial region: gpre[2] -> y1p[2] -> hbp[2] -> zbp[4]
  float* pbuf = (float*)take((size_t)4 * CN * CD * 4);

  // --- input conversion / weight transposition ---
  k_split_cvt<<<dim3(CN * CD / 4 / 256), 256, 0, stream>>>(src, srcH, srcL, CN * CD);
  dim3 tb(32, 8);
  k_transpose_split<<<dim3(CD / 32, CD / 32, 1), tb, 0, stream>>>(q_w, qwH, qwL, CD, CD);
  k_transpose_split<<<dim3(CD / 32, CD / 32, 1), tb, 0, stream>>>(k_w, kwH, kwL, CD, CD);
  k_transpose_split<<<dim3(CD / 32, CD / 32, 1), tb, 0, stream>>>(v_w, vwH, vwL, CD, CD);
  k_transpose_split<<<dim3(CD / 32, CD / 32, 1), tb, 0, stream>>>(gate_w, gwH, gwL, CD, CD);
  k_transpose_split<<<dim3(CD / 32, CD / 32, 1), tb, 0, stream>>>(out_w, owH, owL, CD, CD);
  k_transpose_split<<<dim3(CF / 32, CD / 32, CE), tb, 0, stream>>>(w1, w1t, nullptr, CD, CF);
  k_transpose_split<<<dim3(CD / 32, CF / 32, CE), tb, 0, stream>>>(w2, w2t, nullptr, CF, CD);

  // --- attention ---
  g_qkv<<<dim3(CN / 64, CD / 128, 3), 256, 0, stream>>>(
      srcH, srcL, qwH, qwL, kwH, kwL, vwH, vwL, qH, qL, kH, kL, vTH, vTL);
  k_fattn<<<dim3(CS / 64, CBH), 256, 0, stream>>>(
      qH, qL, kH, kL, vTH, vTL, scale_w, aoH, aoL);
  g_gate<<<dim3(CN / 64, CD / 128, 2), 256, 0, stream>>>(aoH, aoL, gwH, gwL, pbuf);
  k_gatemul<<<dim3(CN * CD / 4 / 256), 256, 0, stream>>>(pbuf, aoH, aoL, gate_b, gdH, gdL);
  g_outp<<<dim3(CN / 64, CD / 128, 2), 256, 0, stream>>>(gdH, gdL, owH, owL, pbuf);
  k_ln1<<<dim3(CN), 256, 0, stream>>>(pbuf, src, n1_g, n1_b, x, xH);

  // --- routing + MoE ---
  k_zero_counts<<<dim3(1), 64, 0, stream>>>(counts);
  k_route<<<dim3(CN / 4), 256, 0, stream>>>(x, moe_gate_w, moe_gate_b, chosen, counts, bucket);
  k_plan<<<dim3(1), 64, 0, stream>>>(counts, tiles);
  g_moe1<<<dim3(40, CF / 128, 2), 256, 0, stream>>>(xH, w1t, counts, bucket, tiles, pbuf);
  k_lngelu<<<dim3(CN), 256, 0, stream>>>(pbuf, chosen, b1, ln_g, ln_b, h2);
  g_moe2<<<dim3(40, CD / 128, 4), 256, 0, stream>>>(h2, w2t, counts, bucket, tiles, pbuf);
  k_ln2<<<dim3(CN), 256, 0, stream>>>(pbuf, x, b2, res_scale, chosen, n2_g, n2_b, outp);
}

// Round 7
// 529.612 us; speedup vs baseline: 1.5080x; 1.0483x over previous
//
#include <hip/hip_runtime.h>

// MemoAI fused block for MI355X (gfx950).
//  - fp16x2 split-precision MFMA (hi + 2^11-scaled lo) upstream of MoE routing
//  - plain fp16 MFMA for the expert FFN (post-routing)
//  - sum(softmax(top2)) == 1 -> moe weight multiplier is exactly 1
//  - only the chosen expert is computed (tokens bucketed by expert)
//  - R1: 64x128 LDS-staged GEMM core (global_load_lds width=16)
//  - R2: flash attention (online softmax, register scores), qscale fused
//  - R3: split-K on gate/outp/moe1/moe2 (partials folded into consumers)
//  - R4: MoE GEMMs: tile-compacted grid (k_plan) + single-barrier dbuf K-loop
//  - R5: fattn K/V staged block-cooperatively into LDS (dbuf, single barrier)
//  - R6: qkv/gate/outp switched to the same single-barrier double-buffered
//    K-loop (split variant, 2x24KB LDS) -- they were the last 2-barrier
//    vmcnt(0)-drain kernels (g_qkv: MfmaUtil 18%, HBM 12%, latency-bound).

typedef _Float16 f16;
typedef _Float16 f16x8 __attribute__((ext_vector_type(8)));
typedef _Float16 f16x4 __attribute__((ext_vector_type(4)));
typedef float f32x4 __attribute__((ext_vector_type(4)));

constexpr int CS  = 1024;  // seq len
constexpr int CD  = 1024;  // model dim
constexpr int CH  = 16;    // heads
constexpr int CHD = 64;    // head dim
constexpr int CF  = 2048;  // ffn dim
constexpr int CE  = 8;     // experts
constexpr int CN  = 2048;  // tokens = B*S
constexpr int CBH = 32;    // B*H
constexpr int KS  = 512;   // split-K slice width
constexpr int MAXT = 48;   // padded tile-table size (true max 39)

constexpr float LO_SCALE = 2048.f;       // 2^11: keeps lo-parts normal in fp16
constexpr float LO_INV   = 1.f / 2048.f;

#define MFMA16(a, b, c) __builtin_amdgcn_mfma_f32_16x16x32_f16((a), (b), (c), 0, 0, 0)

#define TO_GBL(p) ((const __attribute__((address_space(1))) void*)(p))
#define TO_LDS(p) ((__attribute__((address_space(3))) void*)(p))
#define GLD16(g, l) __builtin_amdgcn_global_load_lds(TO_GBL(g), TO_LDS(l), 16, 0, 0)

__device__ __forceinline__ void fsplit(float v, f16 &hi, f16 &lo) {
  hi = (f16)v;
  lo = (f16)((v - (float)hi) * LO_SCALE);
}

// ---------------------------------------------------------------- conversions

__global__ void k_split_cvt(const float* __restrict__ in, f16* __restrict__ oh,
                            f16* __restrict__ ol, int n) {
  int i = (blockIdx.x * blockDim.x + threadIdx.x) * 4;
  if (i >= n) return;
  float4 v = *(const float4*)(in + i);
  float a[4] = {v.x, v.y, v.z, v.w};
#pragma unroll
  for (int j = 0; j < 4; ++j) {
    f16 hi = (f16)a[j];
    oh[i + j] = hi;
    ol[i + j] = (f16)((a[j] - (float)hi) * LO_SCALE);
  }
}

// in: [Z][R][C] f32 -> outH(/outL scaled) : [Z][C][R] f16
__global__ void k_transpose_split(const float* __restrict__ in, f16* __restrict__ oh,
                                  f16* __restrict__ ol, int R, int C) {
  __shared__ float t[32][33];
  const int z = blockIdx.z;
  const float* src = in + (size_t)z * R * C;
  f16* dh = oh + (size_t)z * R * C;
  f16* dl = ol ? ol + (size_t)z * R * C : nullptr;
  const int c0 = blockIdx.x * 32, r0 = blockIdx.y * 32;
  const int tx = threadIdx.x, ty = threadIdx.y;
#pragma unroll
  for (int i = 0; i < 32; i += 8)
    t[ty + i][tx] = src[(size_t)(r0 + ty + i) * C + c0 + tx];
  __syncthreads();
#pragma unroll
  for (int i = 0; i < 32; i += 8) {
    float v = t[tx][ty + i];
    f16 hi = (f16)v;
    size_t idx = (size_t)(c0 + ty + i) * R + r0 + tx;
    dh[idx] = hi;
    if (dl) dl[idx] = (f16)((v - (float)hi) * LO_SCALE);
  }
}

// ------------------------------------------------------------- tiled GEMM core
// Block tile 64(M) x 128(N), BK=32, 4 waves (2x2), wave tile 32x64.
// Single-barrier double-buffered K-loop (R4/R5/R6-proven): prefetch of tile
// k+1 is issued right after the barrier; its vmcnt drain at the NEXT barrier
// overlaps a full tile of ds_read+MFMA. Buffer: SPLIT ? 12288 : 6144 halves
// (Ah | [Al] | Bh | [Bl]), XOR-swizzled 16B chunks (2-way = free).

template <bool SPLIT>
__device__ __forceinline__ void gemm_tile_db(
    const f16* aH, const f16* aL, const f16* bH, const f16* bL,
    size_t bRowStride /* 64*ldb */, int K, f16* lds,
    f32x4 (&accm)[2][4], f32x4 (&accc)[2][4]) {
  constexpr int BUF = SPLIT ? 12288 : 6144;
  constexpr int BOFF = SPLIT ? 4096 : 2048;  // Bh base within buffer
  const int t = threadIdx.x;
  const int lane = t & 63, wave = t >> 6;
  const int wm = wave >> 1, wn = wave & 1;
  const int m16 = lane & 15, quad = lane >> 4;
  int aoff[2], boff[4];
#pragma unroll
  for (int sm = 0; sm < 2; ++sm) {
    const int r = wm * 32 + sm * 16 + m16;
    aoff[sm] = r * 32 + ((quad ^ ((r >> 1) & 3)) * 8);
  }
#pragma unroll
  for (int sn = 0; sn < 4; ++sn) {
    const int r = wn * 64 + sn * 16 + m16;
    boff[sn] = BOFF + r * 32 + ((quad ^ ((r >> 1) & 3)) * 8);
  }
  auto stage = [&](f16* buf) {
    GLD16(aH, buf + t * 8);
    GLD16(bH, buf + BOFF + t * 8);
    GLD16(bH + bRowStride, buf + BOFF + 2048 + t * 8);
    if constexpr (SPLIT) {
      GLD16(aL, buf + 2048 + t * 8);
      GLD16(bL, buf + 8192 + t * 8);
      GLD16(bL + bRowStride, buf + 10240 + t * 8);
      aL += 32; bL += 32;
    }
    aH += 32; bH += 32;
  };
  stage(lds);  // prologue: tile 0 -> buf 0
  int cur = 0;
  for (int k = 0; k < K; k += 32) {
    __syncthreads();  // buf[cur] staged (vmcnt drained) + prev buf consumed
    f16* buf = lds + cur * BUF;
    if (k + 32 < K) stage(lds + (cur ^ 1) * BUF);
    f16x8 af[2], alf[2], bf[4], blf[4];
#pragma unroll
    for (int sm = 0; sm < 2; ++sm) {
      af[sm] = *(const f16x8*)(buf + aoff[sm]);
      if constexpr (SPLIT) alf[sm] = *(const f16x8*)(buf + 2048 + aoff[sm]);
    }
#pragma unroll
    for (int sn = 0; sn < 4; ++sn) {
      bf[sn] = *(const f16x8*)(buf + boff[sn]);
      if constexpr (SPLIT) blf[sn] = *(const f16x8*)(buf + 4096 + boff[sn]);
    }
#pragma unroll
    for (int sm = 0; sm < 2; ++sm)
#pragma unroll
      for (int sn = 0; sn < 4; ++sn) {
        accm[sm][sn] = MFMA16(af[sm], bf[sn], accm[sm][sn]);
        if constexpr (SPLIT) {
          accc[sm][sn] = MFMA16(af[sm], blf[sn], accc[sm][sn]);
          accc[sm][sn] = MFMA16(alf[sm], bf[sn], accc[sm][sn]);
        }
      }
    cur ^= 1;
  }
}

// ---------------------------------------------------------------- QKV

__global__ __launch_bounds__(256) void g_qkv(
    const f16* __restrict__ srcH, const f16* __restrict__ srcL,
    const f16* __restrict__ qwH, const f16* __restrict__ qwL,
    const f16* __restrict__ kwH, const f16* __restrict__ kwL,
    const f16* __restrict__ vwH, const f16* __restrict__ vwL,
    f16* __restrict__ qHo, f16* __restrict__ qLo,
    f16* __restrict__ kHo, f16* __restrict__ kLo,
    f16* __restrict__ vTH, f16* __restrict__ vTL) {
  __shared__ f16 lds[24576];  // 2 x 12288 (split dbuf)
  const int z = blockIdx.z;
  const int m0 = blockIdx.x * 64, n0 = blockIdx.y * 128;
  const int t = threadIdx.x;
  const int rowS = t >> 2;
  const int ksw = ((t & 3) ^ ((rowS >> 1) & 3)) * 8;
  const f16* BH = (z == 0) ? qwH : (z == 1) ? kwH : vwH;
  const f16* BL = (z == 0) ? qwL : (z == 1) ? kwL : vwL;
  const f32x4 VZ = {0.f, 0.f, 0.f, 0.f};
  f32x4 accm[2][4], accc[2][4];
#pragma unroll
  for (int i = 0; i < 2; ++i)
#pragma unroll
    for (int j = 0; j < 4; ++j) { accm[i][j] = VZ; accc[i][j] = VZ; }
  gemm_tile_db<true>(srcH + (size_t)(m0 + rowS) * CD + ksw,
                     srcL + (size_t)(m0 + rowS) * CD + ksw,
                     BH + (size_t)(n0 + rowS) * CD + ksw,
                     BL + (size_t)(n0 + rowS) * CD + ksw,
                     (size_t)64 * CD, CD, lds, accm, accc);
  const int lane = t & 63, wave = t >> 6;
  const int wm = wave >> 1, wn = wave & 1;
  const int m16 = lane & 15, quad = lane >> 4;
#pragma unroll
  for (int sm = 0; sm < 2; ++sm)
#pragma unroll
    for (int sn = 0; sn < 4; ++sn)
#pragma unroll
      for (int r = 0; r < 4; ++r) {
        const int row = m0 + wm * 32 + sm * 16 + quad * 4 + r;  // token
        const int col = n0 + wn * 64 + sn * 16 + m16;           // d
        const float v = accm[sm][sn][r] + accc[sm][sn][r] * LO_INV;
        f16 hi, lo; fsplit(v, hi, lo);
        const int bb = row >> 10, ss = row & 1023;
        const int hh = col >> 6, hd = col & 63;
        if (z == 2) {  // v stored transposed: [b,h,hd,s]
          const size_t idx = ((size_t)((bb * CH + hh) * CHD + hd)) * CS + ss;
          vTH[idx] = hi; vTL[idx] = lo;
        } else {
          const size_t idx = ((size_t)((bb * CH + hh) * CS + ss)) * CHD + hd;
          if (z == 0) { qHo[idx] = hi; qLo[idx] = lo; }
          else        { kHo[idx] = hi; kLo[idx] = lo; }
        }
      }
}

// ------------------------------------------------------- flash attention
// K/V chunk staged block-cooperatively into LDS (dbuf, single barrier,
// source-side XOR swizzle so fragment ds_read_b128 is 2-way = free).

__device__ __forceinline__ int pswz(int q, int k) {
  return q * 64 + ((((k >> 2) ^ q) & 15) << 2) + (k & 3);
}

__global__ __launch_bounds__(256) void k_fattn(
    const f16* __restrict__ qH_, const f16* __restrict__ qL_,
    const f16* __restrict__ kH_, const f16* __restrict__ kL_,
    const f16* __restrict__ vTH_, const f16* __restrict__ vTL_,
    const float* __restrict__ scale_w,
    f16* __restrict__ aoH, f16* __restrict__ aoL) {
  __shared__ f16 kvb[32768];       // 2 x (Khi|Klo|Vhi|Vlo, 4096 halves each)
  __shared__ float psc[4 * 1024];  // 4 waves x (16x64) P tile, swizzled
  const int bh = blockIdx.y;
  const int b = bh >> 4, h = bh & 15;
  const int t = threadIdx.x;
  const int lane = t & 63, wave = t >> 6;
  const int m16 = lane & 15, quad = lane >> 4;
  const int q0 = blockIdx.x * 64 + wave * 16;  // this wave's q rows
  float* P = psc + wave * 1024;
  const f32x4 VZ = {0.f, 0.f, 0.f, 0.f};
  const size_t kb = (size_t)bh * CS * CHD;  // == bh * CHD * CS

  // stage one 64-key chunk (32 KB) into dst
  const int rowS = t >> 3, chS = t & 7;
  auto stage = [&](f16* dst, int kc) {
#pragma unroll
    for (int i = 0; i < 2; ++i) {
      const int row = rowS + 32 * i;
      const int sc = (chS ^ (row & 7)) * 8;
      GLD16(kH_ + kb + (size_t)(kc + row) * CHD + sc, dst + i * 2048 + t * 8);
      GLD16(kL_ + kb + (size_t)(kc + row) * CHD + sc, dst + 4096 + i * 2048 + t * 8);
      GLD16(vTH_ + kb + (size_t)row * CS + kc + sc, dst + 8192 + i * 2048 + t * 8);
      GLD16(vTL_ + kb + (size_t)row * CS + kc + sc, dst + 12288 + i * 2048 + t * 8);
    }
  };
  // fragment read: logical 16B chunk q (0..7) of row r within a 4096-half piece
  auto ldf = [&](const f16* piece, int r, int q) -> f16x8 {
    return *(const f16x8*)(piece + r * 64 + ((q ^ (r & 7)) * 8));
  };

  // Q fragments (A-layout), hi+lo
  const f16* qrh = qH_ + ((size_t)bh * CS + q0 + m16) * CHD + quad * 8;
  const f16* qrl = qL_ + ((size_t)bh * CS + q0 + m16) * CHD + quad * 8;
  f16x8 a0h = *(const f16x8*)(qrh);
  f16x8 a1h = *(const f16x8*)(qrh + 32);
  f16x8 a0l = *(const f16x8*)(qrl);
  f16x8 a1l = *(const f16x8*)(qrl + 32);

  stage(kvb, 0);  // prologue: chunk 0 -> buf 0

  // fused dynamic scale: row factor = 2*sigmoid(q . scale_w[h]) / sqrt(64)
  float dot = 0.f;
  {
    const float* sw = scale_w + h * CHD + quad * 8;
    float4 s0 = *(const float4*)(sw);
    float4 s1 = *(const float4*)(sw + 4);
    float4 s2 = *(const float4*)(sw + 32);
    float4 s3 = *(const float4*)(sw + 36);
    float sv[16] = {s0.x, s0.y, s0.z, s0.w, s1.x, s1.y, s1.z, s1.w,
                    s2.x, s2.y, s2.z, s2.w, s3.x, s3.y, s3.z, s3.w};
#pragma unroll
    for (int j = 0; j < 8; ++j) {
      dot += ((float)a0h[j] + (float)a0l[j] * LO_INV) * sv[j];
      dot += ((float)a1h[j] + (float)a1l[j] * LO_INV) * sv[8 + j];
    }
    dot += __shfl_xor(dot, 16);
    dot += __shfl_xor(dot, 32);
  }
  const float qsv = 2.f / (1.f + __expf(-dot));  // for row q0+m16
  float qsr[4];
#pragma unroll
  for (int r = 0; r < 4; ++r) qsr[r] = __shfl(qsv, quad * 4 + r) * 0.125f;

  f32x4 accm[4], accc[4];  // out accumulator: 4 hd-tiles, C-layout
#pragma unroll
  for (int tt = 0; tt < 4; ++tt) { accm[tt] = VZ; accc[tt] = VZ; }
  float mrun[4], lrun[4];
#pragma unroll
  for (int r = 0; r < 4; ++r) { mrun[r] = -1e30f; lrun[r] = 0.f; }

  int cur = 0;
  for (int kc = 0; kc < CS; kc += 64) {
    __syncthreads();  // buf[cur] staged (vmcnt drained) + prev buf consumed
    const f16* kv = kvb + cur * 16384;
    if (kc + 64 < CS) stage(kvb + (cur ^ 1) * 16384, kc + 64);

    // --- S = (Q K^T) * qs, 4 key tiles (fp32-exact via split)
    f32x4 st[4];
#pragma unroll
    for (int tt = 0; tt < 4; ++tt) {
      const int r = tt * 16 + m16;
      f16x8 b0h = ldf(kv,        r, quad);
      f16x8 b1h = ldf(kv,        r, quad + 4);
      f16x8 b0l = ldf(kv + 4096, r, quad);
      f16x8 b1l = ldf(kv + 4096, r, quad + 4);
      f32x4 am = VZ, ac = VZ;
      am = MFMA16(a0h, b0h, am); am = MFMA16(a1h, b1h, am);
      ac = MFMA16(a0h, b0l, ac); ac = MFMA16(a0l, b0h, ac);
      ac = MFMA16(a1h, b1l, ac); ac = MFMA16(a1l, b1h, ac);
#pragma unroll
      for (int r4 = 0; r4 < 4; ++r4)
        st[tt][r4] = (am[r4] + ac[r4] * LO_INV) * qsr[r4];
    }
    // --- online max update
    float alpha[4];
#pragma unroll
    for (int r = 0; r < 4; ++r) {
      float mx = fmaxf(fmaxf(st[0][r], st[1][r]), fmaxf(st[2][r], st[3][r]));
#pragma unroll
      for (int msk = 8; msk >= 1; msk >>= 1) mx = fmaxf(mx, __shfl_xor(mx, msk));
      const float mnew = fmaxf(mrun[r], mx);
      alpha[r] = __expf(mrun[r] - mnew);
      mrun[r] = mnew;
    }
    // --- exp, row-sum, stash P (C-layout) into wave-private swizzled LDS
    float rs[4] = {0.f, 0.f, 0.f, 0.f};
#pragma unroll
    for (int tt = 0; tt < 4; ++tt)
#pragma unroll
      for (int r = 0; r < 4; ++r) {
        const float e = __expf(st[tt][r] - mrun[r]);
        rs[r] += e;
        P[pswz(quad * 4 + r, tt * 16 + m16)] = e;
      }
#pragma unroll
    for (int r = 0; r < 4; ++r) {
#pragma unroll
      for (int msk = 8; msk >= 1; msk >>= 1) rs[r] += __shfl_xor(rs[r], msk);
      lrun[r] = lrun[r] * alpha[r] + rs[r];
#pragma unroll
      for (int tt = 0; tt < 4; ++tt) { accm[tt][r] *= alpha[r]; accc[tt][r] *= alpha[r]; }
    }
    // --- read P back in A-layout, split hi/lo
    f16x8 pah[2], pal[2];
#pragma unroll
    for (int c = 0; c < 2; ++c) {
      const int k0 = c * 32 + quad * 8;
      float4 p0 = *(const float4*)(P + pswz(m16, k0));
      float4 p1 = *(const float4*)(P + pswz(m16, k0 + 4));
      float pv[8] = {p0.x, p0.y, p0.z, p0.w, p1.x, p1.y, p1.z, p1.w};
#pragma unroll
      for (int j = 0; j < 8; ++j) {
        f16 hi = (f16)pv[j];
        pah[c][j] = hi;
        pal[c][j] = (f16)((pv[j] - (float)hi) * LO_SCALE);
      }
    }
    // --- O += P V  (V^T fragments from LDS)
#pragma unroll
    for (int tt = 0; tt < 4; ++tt) {
      const int r = tt * 16 + m16;  // hd row
#pragma unroll
      for (int c = 0; c < 2; ++c) {
        f16x8 vbh = ldf(kv + 8192,  r, quad + 4 * c);
        f16x8 vbl = ldf(kv + 12288, r, quad + 4 * c);
        accm[tt] = MFMA16(pah[c], vbh, accm[tt]);
        accc[tt] = MFMA16(pah[c], vbl, accc[tt]);
        accc[tt] = MFMA16(pal[c], vbh, accc[tt]);
      }
    }
    cur ^= 1;
  }
  // --- epilogue: normalize by l, split-store
#pragma unroll
  for (int tt = 0; tt < 4; ++tt)
#pragma unroll
    for (int r = 0; r < 4; ++r) {
      const int row = q0 + quad * 4 + r;
      const float v = (accm[tt][r] + accc[tt][r] * LO_INV) / lrun[r];
      f16 hi, lo; fsplit(v, hi, lo);
      const size_t idx = ((size_t)(b * CS + row)) * CD + h * CHD + tt * 16 + m16;
      aoH[idx] = hi; aoL[idx] = lo;
    }
}

// ------------------------------------------- gate / out (split-K partials)

__global__ __launch_bounds__(256) void g_gate(
    const f16* __restrict__ aoH, const f16* __restrict__ aoL,
    const f16* __restrict__ gwH, const f16* __restrict__ gwL,
    float* __restrict__ gpre /* [2][CN*CD] */) {
  __shared__ f16 lds[24576];
  const int m0 = blockIdx.x * 64, n0 = blockIdx.y * 128, s = blockIdx.z;
  const int t = threadIdx.x;
  const int rowS = t >> 2;
  const int ksw = ((t & 3) ^ ((rowS >> 1) & 3)) * 8;
  const int k0 = s * KS;
  const f32x4 VZ = {0.f, 0.f, 0.f, 0.f};
  f32x4 accm[2][4], accc[2][4];
#pragma unroll
  for (int i = 0; i < 2; ++i)
#pragma unroll
    for (int j = 0; j < 4; ++j) { accm[i][j] = VZ; accc[i][j] = VZ; }
  gemm_tile_db<true>(aoH + (size_t)(m0 + rowS) * CD + k0 + ksw,
                     aoL + (size_t)(m0 + rowS) * CD + k0 + ksw,
                     gwH + (size_t)(n0 + rowS) * CD + k0 + ksw,
                     gwL + (size_t)(n0 + rowS) * CD + k0 + ksw,
                     (size_t)64 * CD, KS, lds, accm, accc);
  float* gp = gpre + (size_t)s * CN * CD;
  const int lane = t & 63, wave = t >> 6;
  const int wm = wave >> 1, wn = wave & 1;
  const int m16 = lane & 15, quad = lane >> 4;
#pragma unroll
  for (int sm = 0; sm < 2; ++sm)
#pragma unroll
    for (int sn = 0; sn < 4; ++sn)
#pragma unroll
      for (int r = 0; r < 4; ++r) {
        const int row = m0 + wm * 32 + sm * 16 + quad * 4 + r;
        const int col = n0 + wn * 64 + sn * 16 + m16;
        gp[(size_t)row * CD + col] = accm[sm][sn][r] + accc[sm][sn][r] * LO_INV;
      }
}

// gd = fsplit(ao * sigmoid(gpre0+gpre1+gate_b))
__global__ __launch_bounds__(256) void k_gatemul(
    const float* __restrict__ gpre, const f16* __restrict__ aoH,
    const f16* __restrict__ aoL, const float* __restrict__ gate_b,
    f16* __restrict__ gdH, f16* __restrict__ gdL) {
  const int i = (blockIdx.x * 256 + threadIdx.x) * 4;
  float4 p0 = *(const float4*)(gpre + i);
  float4 p1 = *(const float4*)(gpre + (size_t)CN * CD + i);
  float4 gb = *(const float4*)(gate_b + (i & (CD - 1)));
  f16x4 ah = *(const f16x4*)(aoH + i);
  f16x4 al = *(const f16x4*)(aoL + i);
  float pre[4] = {p0.x + p1.x + gb.x, p0.y + p1.y + gb.y,
                  p0.z + p1.z + gb.z, p0.w + p1.w + gb.w};
  f16x4 oh, ol;
#pragma unroll
  for (int j = 0; j < 4; ++j) {
    const float g = 1.f / (1.f + __expf(-pre[j]));
    const float ov = ((float)ah[j] + (float)al[j] * LO_INV) * g;
    f16 hi, lo; fsplit(ov, hi, lo);
    oh[j] = hi; ol[j] = lo;
  }
  *(f16x4*)(gdH + i) = oh;
  *(f16x4*)(gdL + i) = ol;
}

__global__ __launch_bounds__(256) void g_outp(
    const f16* __restrict__ gdH, const f16* __restrict__ gdL,
    const f16* __restrict__ owH, const f16* __restrict__ owL,
    float* __restrict__ y1p /* [2][CN*CD] */) {
  __shared__ f16 lds[24576];
  const int m0 = blockIdx.x * 64, n0 = blockIdx.y * 128, s = blockIdx.z;
  const int t = threadIdx.x;
  const int rowS = t >> 2;
  const int ksw = ((t & 3) ^ ((rowS >> 1) & 3)) * 8;
  const int k0 = s * KS;
  const f32x4 VZ = {0.f, 0.f, 0.f, 0.f};
  f32x4 accm[2][4], accc[2][4];
#pragma unroll
  for (int i = 0; i < 2; ++i)
#pragma unroll
    for (int j = 0; j < 4; ++j) { accm[i][j] = VZ; accc[i][j] = VZ; }
  gemm_tile_db<true>(gdH + (size_t)(m0 + rowS) * CD + k0 + ksw,
                     gdL + (size_t)(m0 + rowS) * CD + k0 + ksw,
                     owH + (size_t)(n0 + rowS) * CD + k0 + ksw,
                     owL + (size_t)(n0 + rowS) * CD + k0 + ksw,
                     (size_t)64 * CD, KS, lds, accm, accc);
  float* yp = y1p + (size_t)s * CN * CD;
  const int lane = t & 63, wave = t >> 6;
  const int wm = wave >> 1, wn = wave & 1;
  const int m16 = lane & 15, quad = lane >> 4;
#pragma unroll
  for (int sm = 0; sm < 2; ++sm)
#pragma unroll
    for (int sn = 0; sn < 4; ++sn)
#pragma unroll
      for (int r = 0; r < 4; ++r) {
        const int row = m0 + wm * 32 + sm * 16 + quad * 4 + r;
        const int col = n0 + wn * 64 + sn * 16 + m16;
        yp[(size_t)row * CD + col] = accm[sm][sn][r] + accc[sm][sn][r] * LO_INV;
      }
}

// -------------------------------------------------------------- layernorms

__device__ __forceinline__ void block_reduce2(float &s, float &ss, float* red) {
#pragma unroll
  for (int msk = 32; msk >= 1; msk >>= 1) {
    s += __shfl_xor(s, msk);
    ss += __shfl_xor(ss, msk);
  }
  const int wave = threadIdx.x >> 6, lane = threadIdx.x & 63;
  if (lane == 0) { red[wave] = s; red[4 + wave] = ss; }
  __syncthreads();
  s = red[0] + red[1] + red[2] + red[3];
  ss = red[4] + red[5] + red[6] + red[7];
}

// x = LN(src + y1p0 + y1p1)
__global__ __launch_bounds__(256) void k_ln1(
    const float* __restrict__ y1p, const float* __restrict__ srcp,
    const float* __restrict__ g, const float* __restrict__ bb,
    float* __restrict__ x, f16* __restrict__ xH) {
  __shared__ float red[8];
  const int n = blockIdx.x;
  const int t = threadIdx.x;
  const size_t off = (size_t)n * CD + t * 4;
  float4 v0 = *(const float4*)(y1p + off);
  float4 v1 = *(const float4*)(y1p + (size_t)CN * CD + off);
  float4 v2 = *(const float4*)(srcp + off);
  float a[4] = {v0.x + v1.x + v2.x, v0.y + v1.y + v2.y,
                v0.z + v1.z + v2.z, v0.w + v1.w + v2.w};
  float s = a[0] + a[1] + a[2] + a[3];
  float ss = a[0]*a[0] + a[1]*a[1] + a[2]*a[2] + a[3]*a[3];
  block_reduce2(s, ss, red);
  const float mean = s * (1.f / CD);
  const float var = ss * (1.f / CD) - mean * mean;
  const float rstd = rsqrtf(var + 1e-5f);
#pragma unroll
  for (int j = 0; j < 4; ++j) {
    const int d = t * 4 + j;
    const float val = (a[j] - mean) * rstd * g[d] + bb[d];
    x[(size_t)n * CD + d] = val;
    xH[(size_t)n * CD + d] = (f16)val;
  }
}

// out = LN2( 2*x + (zbp0+..+zbp3 + b2[e])*rs[e] )
__global__ __launch_bounds__(256) void k_ln2(
    const float* __restrict__ zbp, const float* __restrict__ x,
    const float* __restrict__ b2, const float* __restrict__ rsc,
    const int* __restrict__ chosen,
    const float* __restrict__ g, const float* __restrict__ bb,
    float* __restrict__ outp) {
  __shared__ float red[8];
  const int n = blockIdx.x;
  const int e = chosen[n];
  const float rs = rsc[e];
  const int t = threadIdx.x;
  const size_t off = (size_t)n * CD + t * 4;
  float4 p0 = *(const float4*)(zbp + off);
  float4 p1 = *(const float4*)(zbp + (size_t)CN * CD + off);
  float4 p2 = *(const float4*)(zbp + (size_t)2 * CN * CD + off);
  float4 p3 = *(const float4*)(zbp + (size_t)3 * CN * CD + off);
  float4 xv = *(const float4*)(x + off);
  float4 bv = *(const float4*)(b2 + (size_t)e * CD + t * 4);
  float a[4] = {2.f * xv.x + (p0.x + p1.x + p2.x + p3.x + bv.x) * rs,
                2.f * xv.y + (p0.y + p1.y + p2.y + p3.y + bv.y) * rs,
                2.f * xv.z + (p0.z + p1.z + p2.z + p3.z + bv.z) * rs,
                2.f * xv.w + (p0.w + p1.w + p2.w + p3.w + bv.w) * rs};
  float s = a[0] + a[1] + a[2] + a[3];
  float ss = a[0]*a[0] + a[1]*a[1] + a[2]*a[2] + a[3]*a[3];
  block_reduce2(s, ss, red);
  const float mean = s * (1.f / CD);
  const float var = ss * (1.f / CD) - mean * mean;
  const float rstd = rsqrtf(var + 1e-5f);
#pragma unroll
  for (int j = 0; j < 4; ++j) {
    const int d = t * 4 + j;
    outp[(size_t)n * CD + d] = (a[j] - mean) * rstd * g[d] + bb[d];
  }
}

// ------------------------------------------------------------------ routing

__global__ void k_zero_counts(int* counts) {
  if (threadIdx.x < CE) counts[threadIdx.x] = 0;
}

__global__ __launch_bounds__(256) void k_route(
    const float* __restrict__ x, const float* __restrict__ gw, const float* __restrict__ gb,
    int* __restrict__ chosen, int* __restrict__ counts, int* __restrict__ bucket) {
  const int wave = threadIdx.x >> 6, lane = threadIdx.x & 63;
  const int n = blockIdx.x * 4 + wave;
  const float* xr = x + (size_t)n * CD;
  float acc[CE];
#pragma unroll
  for (int e = 0; e < CE; ++e) acc[e] = 0.f;
  for (int j = 0; j < 16; ++j) {
    const int d = lane * 16 + j;
    const float xv = xr[d];
    const float* wr = gw + (size_t)d * CE;
#pragma unroll
    for (int e = 0; e < CE; ++e) acc[e] += xv * wr[e];
  }
#pragma unroll
  for (int msk = 32; msk >= 1; msk >>= 1) {
#pragma unroll
    for (int e = 0; e < CE; ++e) acc[e] += __shfl_xor(acc[e], msk);
  }
  if (lane == 0) {
    float best = -1e30f, second = -1e30f;
    int bi = 0, si = 0;
#pragma unroll
    for (int e = 0; e < CE; ++e) {
      const float L = acc[e] + gb[e];
      if (L > best) { second = best; si = bi; best = L; bi = e; }
      else if (L > second) { second = L; si = e; }
    }
    const int ch = bi > si ? bi : si;  // torch-loop semantics: max index wins
    chosen[n] = ch;
    const int pos = atomicAdd(&counts[ch], 1);
    bucket[ch * CN + pos] = n;
  }
}

// build dense tile table: (expert, m0) for every 64-row tile of every expert
__global__ void k_plan(const int* __restrict__ counts, int* __restrict__ tiles) {
  if (threadIdx.x == 0) {
    int n = 0;
    for (int e = 0; e < CE; ++e) {
      const int c = counts[e];
      for (int m0 = 0; m0 < c; m0 += 64) { tiles[2 * n] = e; tiles[2 * n + 1] = m0; ++n; }
    }
    for (; n < MAXT; ++n) { tiles[2 * n] = -1; tiles[2 * n + 1] = 0; }
  }
}

// ------------------------------------------------------------------ MoE FFN

__global__ __launch_bounds__(256) void g_moe1(
    const f16* __restrict__ xH, const f16* __restrict__ w1t,
    const int* __restrict__ counts, const int* __restrict__ bucket,
    const int* __restrict__ tiles, float* __restrict__ hbp /* [2][CN*CF] */) {
  const int e = tiles[2 * blockIdx.x];
  if (e < 0) return;
  const int m0 = tiles[2 * blockIdx.x + 1];
  const int cnt = counts[e];
  const int s = blockIdx.z;
  __shared__ f16 lds[12288];  // 2 x 6144 (dbuf)
  const int t = threadIdx.x;
  const int rowS = t >> 2;
  const int ksw = ((t & 3) ^ ((rowS >> 1) & 3)) * 8;
  const int k0 = s * KS;
  int ra = m0 + rowS; if (ra > cnt - 1) ra = cnt - 1;
  const int tokA = bucket[e * CN + ra];
  const int n0 = blockIdx.y * 128;
  const f32x4 VZ = {0.f, 0.f, 0.f, 0.f};
  f32x4 accm[2][4], accd[2][4];
#pragma unroll
  for (int i = 0; i < 2; ++i)
#pragma unroll
    for (int j = 0; j < 4; ++j) { accm[i][j] = VZ; accd[i][j] = VZ; }
  gemm_tile_db<false>(xH + (size_t)tokA * CD + k0 + ksw, nullptr,
                      w1t + ((size_t)e * CF + n0 + rowS) * CD + k0 + ksw, nullptr,
                      (size_t)64 * CD, KS, lds, accm, accd);
  float* hp = hbp + (size_t)s * CN * CF;
  const int lane = t & 63, wave = t >> 6;
  const int wm = wave >> 1, wn = wave & 1;
  const int m16 = lane & 15, quad = lane >> 4;
#pragma unroll
  for (int sm = 0; sm < 2; ++sm)
#pragma unroll
    for (int sn = 0; sn < 4; ++sn)
#pragma unroll
      for (int r = 0; r < 4; ++r) {
        const int rr = m0 + wm * 32 + sm * 16 + quad * 4 + r;
        if (rr >= cnt) continue;
        const int tok = bucket[e * CN + rr];
        const int col = n0 + wn * 64 + sn * 16 + m16;
        hp[(size_t)tok * CF + col] = accm[sm][sn][r];
      }
}

// h2 = gelu(LN_e(hbp0+hbp1+b1[e]))
__global__ __launch_bounds__(256) void k_lngelu(
    const float* __restrict__ hbp, const int* __restrict__ chosen,
    const float* __restrict__ b1,
    const float* __restrict__ ln_g, const float* __restrict__ ln_b,
    f16* __restrict__ h2) {
  __shared__ float red[8];
  const int n = blockIdx.x;
  const int e = chosen[n];
  const int t = threadIdx.x;
  const size_t off = (size_t)n * CF + t * 8;
  float4 v0 = *(const float4*)(hbp + off);
  float4 v1 = *(const float4*)(hbp + off + 4);
  float4 u0 = *(const float4*)(hbp + (size_t)CN * CF + off);
  float4 u1 = *(const float4*)(hbp + (size_t)CN * CF + off + 4);
  float4 b0 = *(const float4*)(b1 + (size_t)e * CF + t * 8);
  float4 b1v = *(const float4*)(b1 + (size_t)e * CF + t * 8 + 4);
  float a[8] = {v0.x + u0.x + b0.x, v0.y + u0.y + b0.y,
                v0.z + u0.z + b0.z, v0.w + u0.w + b0.w,
                v1.x + u1.x + b1v.x, v1.y + u1.y + b1v.y,
                v1.z + u1.z + b1v.z, v1.w + u1.w + b1v.w};
  float s = 0.f, ss = 0.f;
#pragma unroll
  for (int j = 0; j < 8; ++j) { s += a[j]; ss += a[j] * a[j]; }
  block_reduce2(s, ss, red);
  const float mean = s * (1.f / CF);
  const float var = ss * (1.f / CF) - mean * mean;
  const float rstd = rsqrtf(var + 1e-5f);
  const float* g = ln_g + (size_t)e * CF;
  const float* bb = ln_b + (size_t)e * CF;
#pragma unroll
  for (int j = 0; j < 8; ++j) {
    const int d = t * 8 + j;
    const float val = (a[j] - mean) * rstd * g[d] + bb[d];
    const float gl = 0.5f * val * (1.f + erff(val * 0.70710678118654752f));
    h2[(size_t)n * CF + d] = (f16)gl;
  }
}

__global__ __launch_bounds__(256) void g_moe2(
    const f16* __restrict__ h2, const f16* __restrict__ w2t,
    const int* __restrict__ counts, const int* __restrict__ bucket,
    const int* __restrict__ tiles, float* __restrict__ zbp /* [4][CN*CD] */) {
  const int e = tiles[2 * blockIdx.x];
  if (e < 0) return;
  const int m0 = tiles[2 * blockIdx.x + 1];
  const int cnt = counts[e];
  const int s = blockIdx.z;
  __shared__ f16 lds[12288];  // 2 x 6144 (dbuf)
  const int t = threadIdx.x;
  const int rowS = t >> 2;
  const int ksw = ((t & 3) ^ ((rowS >> 1) & 3)) * 8;
  const int k0 = s * KS;
  int ra = m0 + rowS; if (ra > cnt - 1) ra = cnt - 1;
  const int tokA = bucket[e * CN + ra];
  const int n0 = blockIdx.y * 128;
  const f32x4 VZ = {0.f, 0.f, 0.f, 0.f};
  f32x4 accm[2][4], accd[2][4];
#pragma unroll
  for (int i = 0; i < 2; ++i)
#pragma unroll
    for (int j = 0; j < 4; ++j) { accm[i][j] = VZ; accd[i][j] = VZ; }
  gemm_tile_db<false>(h2 + (size_t)tokA * CF + k0 + ksw, nullptr,
                      w2t + ((size_t)e * CD + n0 + rowS) * CF + k0 + ksw, nullptr,
                      (size_t)64 * CF, KS, lds, accm, accd);
  float* zp = zbp + (size_t)s * CN * CD;
  const int lane = t & 63, wave = t >> 6;
  const int wm = wave >> 1, wn = wave & 1;
  const int m16 = lane & 15, quad = lane >> 4;
#pragma unroll
  for (int sm = 0; sm < 2; ++sm)
#pragma unroll
    for (int sn = 0; sn < 4; ++sn)
#pragma unroll
      for (int r = 0; r < 4; ++r) {
        const int rr = m0 + wm * 32 + sm * 16 + quad * 4 + r;
        if (rr >= cnt) continue;
        const int tok = bucket[e * CN + rr];
        const int col = n0 + wn * 64 + sn * 16 + m16;
        zp[(size_t)tok * CD + col] = accm[sm][sn][r];
      }
}

// ------------------------------------------------------------------- launch

extern "C" void kernel_launch(void* const* d_in, const int* in_sizes, int n_in,
                              void* d_out, int out_size, void* d_ws, size_t ws_size,
                              hipStream_t stream) {
  (void)in_sizes; (void)n_in; (void)out_size; (void)ws_size;
  const float* src        = (const float*)d_in[0];
  const float* q_w        = (const float*)d_in[1];
  const float* k_w        = (const float*)d_in[2];
  const float* v_w        = (const float*)d_in[3];
  const float* out_w      = (const float*)d_in[4];
  const float* gate_w     = (const float*)d_in[5];
  const float* gate_b     = (const float*)d_in[6];
  const float* scale_w    = (const float*)d_in[7];
  const float* n1_g       = (const float*)d_in[8];
  const float* n1_b       = (const float*)d_in[9];
  const float* n2_g       = (const float*)d_in[10];
  const float* n2_b       = (const float*)d_in[11];
  const float* moe_gate_w = (const float*)d_in[12];
  const float* moe_gate_b = (const float*)d_in[13];
  const float* w1         = (const float*)d_in[14];
  const float* b1         = (const float*)d_in[15];
  const float* ln_g       = (const float*)d_in[16];
  const float* ln_b       = (const float*)d_in[17];
  const float* w2         = (const float*)d_in[18];
  const float* b2         = (const float*)d_in[19];
  const float* res_scale  = (const float*)d_in[20];
  float* outp = (float*)d_out;

  char* p = (char*)d_ws;
  auto take = [&](size_t bytes) -> char* {
    char* r = p;
    p += (bytes + 255) & ~(size_t)255;
    return r;
  };
  f16* srcH = (f16*)take((size_t)CN * CD * 2);
  f16* srcL = (f16*)take((size_t)CN * CD * 2);
  f16* qwH = (f16*)take((size_t)CD * CD * 2);
  f16* qwL = (f16*)take((size_t)CD * CD * 2);
  f16* kwH = (f16*)take((size_t)CD * CD * 2);
  f16* kwL = (f16*)take((size_t)CD * CD * 2);
  f16* vwH = (f16*)take((size_t)CD * CD * 2);
  f16* vwL = (f16*)take((size_t)CD * CD * 2);
  f16* gwH = (f16*)take((size_t)CD * CD * 2);
  f16* gwL = (f16*)take((size_t)CD * CD * 2);
  f16* owH = (f16*)take((size_t)CD * CD * 2);
  f16* owL = (f16*)take((size_t)CD * CD * 2);
  f16* qH = (f16*)take((size_t)CBH * CS * CHD * 2);
  f16* qL = (f16*)take((size_t)CBH * CS * CHD * 2);
  f16* kH = (f16*)take((size_t)CBH * CS * CHD * 2);
  f16* kL = (f16*)take((size_t)CBH * CS * CHD * 2);
  f16* vTH = (f16*)take((size_t)CBH * CS * CHD * 2);
  f16* vTL = (f16*)take((size_t)CBH * CS * CHD * 2);
  f16* aoH = (f16*)take((size_t)CN * CD * 2);
  f16* aoL = (f16*)take((size_t)CN * CD * 2);
  f16* gdH = (f16*)take((size_t)CN * CD * 2);
  f16* gdL = (f16*)take((size_t)CN * CD * 2);
  float* x  = (float*)take((size_t)CN * CD * 4);
  f16* xH = (f16*)take((size_t)CN * CD * 2);
  int* counts = (int*)take(64);
  int* bucket = (int*)take((size_t)CE * CN * 4);
  int* chosen = (int*)take((size_t)CN * 4);
  int* tiles = (int*)take((size_t)MAXT * 2 * 4);
  f16* h2 = (f16*)take((size_t)CN * CF * 2);
  f16* w1t = (f16*)take((size_t)CE * CF * CD * 2);
  f16* w2t = (f16*)take((size_t)CE * CD * CF * 2);
  // time-shared 32 MB fp32 partial region: gpre[2] -> y1p[2] -> hbp[2] -> zbp[4]
  float* pbuf = (float*)take((size_t)4 * CN * CD * 4);

  // --- input conversion / weight transposition ---
  k_split_cvt<<<dim3(CN * CD / 4 / 256), 256, 0, stream>>>(src, srcH, srcL, CN * CD);
  dim3 tb(32, 8);
  k_transpose_split<<<dim3(CD / 32, CD / 32, 1), tb, 0, stream>>>(q_w, qwH, qwL, CD, CD);
  k_transpose_split<<<dim3(CD / 32, CD / 32, 1), tb, 0, stream>>>(k_w, kwH, kwL, CD, CD);
  k_transpose_split<<<dim3(CD / 32, CD / 32, 1), tb, 0, stream>>>(v_w, vwH, vwL, CD, CD);
  k_transpose_split<<<dim3(CD / 32, CD / 32, 1), tb, 0, stream>>>(gate_w, gwH, gwL, CD, CD);
  k_transpose_split<<<dim3(CD / 32, CD / 32, 1), tb, 0, stream>>>(out_w, owH, owL, CD, CD);
  k_transpose_split<<<dim3(CF / 32, CD / 32, CE), tb, 0, stream>>>(w1, w1t, nullptr, CD, CF);
  k_transpose_split<<<dim3(CD / 32, CF / 32, CE), tb, 0, stream>>>(w2, w2t, nullptr, CF, CD);

  // --- attention ---
  g_qkv<<<dim3(CN / 64, CD / 128, 3), 256, 0, stream>>>(
      srcH, srcL, qwH, qwL, kwH, kwL, vwH, vwL, qH, qL, kH, kL, vTH, vTL);
  k_fattn<<<dim3(CS / 64, CBH), 256, 0, stream>>>(
      qH, qL, kH, kL, vTH, vTL, scale_w, aoH, aoL);
  g_gate<<<dim3(CN / 64, CD / 128, 2), 256, 0, stream>>>(aoH, aoL, gwH, gwL, pbuf);
  k_gatemul<<<dim3(CN * CD / 4 / 256), 256, 0, stream>>>(pbuf, aoH, aoL, gate_b, gdH, gdL);
  g_outp<<<dim3(CN / 64, CD / 128, 2), 256, 0, stream>>>(gdH, gdL, owH, owL, pbuf);
  k_ln1<<<dim3(CN), 256, 0, stream>>>(pbuf, src, n1_g, n1_b, x, xH);

  // --- routing + MoE ---
  k_zero_counts<<<dim3(1), 64, 0, stream>>>(counts);
  k_route<<<dim3(CN / 4), 256, 0, stream>>>(x, moe_gate_w, moe_gate_b, chosen, counts, bucket);
  k_plan<<<dim3(1), 64, 0, stream>>>(counts, tiles);
  g_moe1<<<dim3(40, CF / 128, 2), 256, 0, stream>>>(xH, w1t, counts, bucket, tiles, pbuf);
  k_lngelu<<<dim3(CN), 256, 0, stream>>>(pbuf, chosen, b1, ln_g, ln_b, h2);
  g_moe2<<<dim3(40, CD / 128, 4), 256, 0, stream>>>(h2, w2t, counts, bucket, tiles, pbuf);
  k_ln2<<<dim3(CN), 256, 0, stream>>>(pbuf, x, b2, res_scale, chosen, n2_g, n2_b, outp);
}